// Round 8
// baseline (1860.008 us; speedup 1.0000x reference)
//
#include <hip/hip_runtime.h>
#include <cstdio>
#include <cstdint>

#define N_NODES 100000
#define N_EDGES 600000
#define DIM     128
#define NSETS   3
#define NLAYERS 2
#define NGRAPH  64
#define NPASS   2
#define SP      136       // LDS row stride in shorts
#define GT      3125      // gather tiles (32 nodes each)
#define MT      1563      // gemm tiles (64 nodes each)

typedef __bf16 bf16x8 __attribute__((ext_vector_type(8)));
typedef float  f32x4  __attribute__((ext_vector_type(4)));
typedef unsigned short u16;

static __device__ __forceinline__ float bf2f(u16 u) {
    return __uint_as_float(((uint32_t)u) << 16);
}
static __device__ __forceinline__ u16 f2bf(float f) {
    uint32_t u = __float_as_uint(f);
    uint32_t r = (u + 0x7FFFu + ((u >> 16) & 1u)) >> 16;
    return (u16)r;
}
static __device__ __forceinline__ uint32_t packbf(float lo, float hi) {
    return (uint32_t)f2bf(lo) | ((uint32_t)f2bf(hi) << 16);
}
static __device__ __forceinline__ void unpack_add(uint32_t u, float& a0, float& a1) {
    a0 += __uint_as_float(u << 16);
    a1 += __uint_as_float(u & 0xFFFF0000u);
}
static __device__ __forceinline__ float unpk(uint32_t u, int idx) {
    return idx ? __uint_as_float(u & 0xFFFF0000u) : __uint_as_float(u << 16);
}
static __device__ __forceinline__ float sigmoidf_(float x) {
    return 1.0f / (1.0f + __expf(-x));
}
static __device__ __forceinline__ float tanhf_(float x) {
    return 1.0f - 2.0f / (__expf(2.0f * x) + 1.0f);
}

// ---------------- dtype detection ----------------
__global__ void k_detect(const u16* __restrict__ x, int* __restrict__ flag) {
    __shared__ float red[256];
    float m = 0.0f;
    for (int i = threadIdx.x; i < 8192; i += 256) {
        float f = __uint_as_float(((uint32_t)x[i]) << 16);
        f = fabsf(f);
        if (isnan(f)) f = 3.0e38f;
        m = fmaxf(m, f);
    }
    red[threadIdx.x] = m;
    __syncthreads();
    for (int off = 128; off > 0; off >>= 1) {
        if (threadIdx.x < off) red[threadIdx.x] = fmaxf(red[threadIdx.x], red[threadIdx.x + off]);
        __syncthreads();
    }
    if (threadIdx.x == 0) flag[0] = (red[0] < 1.0e6f) ? 1 : 0;
}

// ---------------- converts ----------------
__global__ void k_convert(const void* __restrict__ src, float* __restrict__ dst,
                          int n, const int* __restrict__ flag) {
    const int f = *flag;
    for (int i = blockIdx.x * blockDim.x + threadIdx.x; i < n; i += gridDim.x * blockDim.x) {
        float v;
        if (f) v = bf2f(((const u16*)src)[i]);
        else   v = ((const float*)src)[i];
        dst[i] = v;
    }
}

__global__ void k_to_bf(const void* __restrict__ src, u16* __restrict__ dst,
                        int n, const int* __restrict__ flag) {
    const int f = *flag;
    for (int i = blockIdx.x * blockDim.x + threadIdx.x; i < n; i += gridDim.x * blockDim.x) {
        if (f) dst[i] = ((const u16*)src)[i];
        else   dst[i] = f2bf(((const float*)src)[i]);
    }
}

// W raw [S][L][j][d] -> Wt fp32 [sl][d][j]
__global__ void k_transW(const void* __restrict__ src, float* __restrict__ dst,
                         const int* __restrict__ flag) {
    const int total = NSETS * NLAYERS * DIM * DIM;
    const int f = *flag;
    for (int i = blockIdx.x * blockDim.x + threadIdx.x; i < total; i += gridDim.x * blockDim.x) {
        const int sl = i >> 14;
        const int rem = i & 16383;
        const int d = rem >> 7;
        const int j = rem & 127;
        const int si = (sl << 14) + j * 128 + d;
        float v;
        if (f) v = bf2f(((const u16*)src)[si]);
        else   v = ((const float*)src)[si];
        dst[i] = v;
    }
}

// Wf[sl][n][j] = sum_d wih[s][n][d] * Wt[sl][d][j]
__global__ void k_fuse(const float* __restrict__ Wt, const void* __restrict__ wih_raw,
                       u16* __restrict__ hi, u16* __restrict__ lo,
                       const int* __restrict__ flag) {
    const int f = *flag;
    const int i = blockIdx.x * 256 + threadIdx.x;
    const int sl = i / 49152;
    const int rem = i - sl * 49152;
    const int n = rem >> 7;
    const int j = rem & 127;
    const int s = sl >> 1;
    const float* wt = Wt + (sl << 14) + j;
    const int wb = (s * 384 + n) * 128;
    float acc = 0.0f;
#pragma unroll 8
    for (int d = 0; d < 128; ++d) {
        float wv;
        if (f) wv = bf2f(((const u16*)wih_raw)[wb + d]);
        else   wv = ((const float*)wih_raw)[wb + d];
        acc = fmaf(wv, wt[d * 128], acc);
    }
    u16 h = f2bf(acc);
    hi[i] = h;
    lo[i] = f2bf(acc - bf2f(h));
}

// whh: [S][384][128] -> hi/lo bf16
__global__ void k_prep_G(const void* __restrict__ src, u16* __restrict__ hi,
                         u16* __restrict__ lo, const int* __restrict__ flag) {
    const int total = NSETS * 384 * DIM;
    const int f = *flag;
    for (int i = blockIdx.x * blockDim.x + threadIdx.x; i < total; i += gridDim.x * blockDim.x) {
        float v;
        if (f) v = bf2f(((const u16*)src)[i]);
        else   v = ((const float*)src)[i];
        u16 h = f2bf(v);
        hi[i] = h;
        lo[i] = f2bf(v - bf2f(h));
    }
}

// ---------------- CSR build ----------------
__global__ void k_deg(const int* __restrict__ ei, const int* __restrict__ attr,
                      int* __restrict__ cnt) {
    int e = blockIdx.x * 256 + threadIdx.x;
    if (e < N_EDGES) {
        int t = attr[e];
        int d = ei[N_EDGES + e];
        atomicAdd(&cnt[t * N_NODES + d], 1);
    }
}

__global__ void k_scan1(const int* __restrict__ cnt, int* __restrict__ rp,
                        int* __restrict__ part, int n) {
    __shared__ int buf[1024];
    int gid = blockIdx.x * 1024 + threadIdx.x;
    int v = (gid < n) ? cnt[gid] : 0;
    buf[threadIdx.x] = v;
    __syncthreads();
    for (int off = 1; off < 1024; off <<= 1) {
        int t = (threadIdx.x >= off) ? buf[threadIdx.x - off] : 0;
        __syncthreads();
        buf[threadIdx.x] += t;
        __syncthreads();
    }
    if (gid < n) rp[gid] = buf[threadIdx.x] - v;
    if (threadIdx.x == 1023) part[blockIdx.x] = buf[1023];
}

__global__ void k_scan2(int* __restrict__ part, int nb) {
    __shared__ int buf[1024];
    int v = (threadIdx.x < nb) ? part[threadIdx.x] : 0;
    buf[threadIdx.x] = v;
    __syncthreads();
    for (int off = 1; off < 1024; off <<= 1) {
        int t = (threadIdx.x >= off) ? buf[threadIdx.x - off] : 0;
        __syncthreads();
        buf[threadIdx.x] += t;
        __syncthreads();
    }
    if (threadIdx.x < nb) part[threadIdx.x] = buf[threadIdx.x] - v;
}

__global__ void k_scan3(int* __restrict__ rp, int* __restrict__ cursor,
                        const int* __restrict__ part, int n) {
    int gid = blockIdx.x * 1024 + threadIdx.x;
    if (gid < n) {
        int v = rp[gid] + part[blockIdx.x];
        rp[gid] = v;
        cursor[gid] = v;
    }
    if (gid == 0) rp[n] = N_EDGES;
}

__global__ void k_fill(const int* __restrict__ ei, const int* __restrict__ attr,
                       int* __restrict__ cursor, int* __restrict__ col) {
    int e = blockIdx.x * 256 + threadIdx.x;
    if (e < N_EDGES) {
        int t = attr[e];
        int d = ei[N_EDGES + e];
        int s = ei[e];
        int pos = atomicAdd(&cursor[t * N_NODES + d], 1);
        col[pos] = s;
    }
}

// ---------------- gather ----------------
__global__ void __launch_bounds__(256, 6)
k_gather(const u16* __restrict__ s0, const u16* __restrict__ s1, const u16* __restrict__ s2,
         u16* __restrict__ d0, u16* __restrict__ d1, u16* __restrict__ d2,
         const int* __restrict__ rp, const int* __restrict__ colarr) {
    const int bx = blockIdx.x;
    const int set = bx / GT;
    const int tile = bx - set * GT;
    const u16* __restrict__ src = (set == 0) ? s0 : (set == 1) ? s1 : s2;
    u16* __restrict__ dst = (set == 0) ? d0 : (set == 1) ? d1 : d2;
    const int* __restrict__ rp_s = rp + set * N_NODES;

    const int nl = threadIdx.x >> 3;
    const int q  = threadIdx.x & 7;
    const int gn = tile * 32 + nl;

    float a[16];
#pragma unroll
    for (int j = 0; j < 16; ++j) a[j] = 0.0f;

    const int beg = rp_s[gn], end = rp_s[gn + 1];
    int dg = end - beg; if (dg < 1) dg = 1;
    const float inv = 1.0f / (float)dg;

    int e = beg;
    for (; e + 2 <= end; e += 2) {
        const int c0 = colarr[e];
        const int c1 = colarr[e + 1];
        const uint4* m0 = (const uint4*)(src + (size_t)c0 * DIM + q * 16);
        const uint4* m1 = (const uint4*)(src + (size_t)c1 * DIM + q * 16);
        uint4 v0 = m0[0], v1 = m0[1], w0 = m1[0], w1 = m1[1];
        unpack_add(v0.x, a[0], a[1]);   unpack_add(v0.y, a[2], a[3]);
        unpack_add(v0.z, a[4], a[5]);   unpack_add(v0.w, a[6], a[7]);
        unpack_add(v1.x, a[8], a[9]);   unpack_add(v1.y, a[10], a[11]);
        unpack_add(v1.z, a[12], a[13]); unpack_add(v1.w, a[14], a[15]);
        unpack_add(w0.x, a[0], a[1]);   unpack_add(w0.y, a[2], a[3]);
        unpack_add(w0.z, a[4], a[5]);   unpack_add(w0.w, a[6], a[7]);
        unpack_add(w1.x, a[8], a[9]);   unpack_add(w1.y, a[10], a[11]);
        unpack_add(w1.z, a[12], a[13]); unpack_add(w1.w, a[14], a[15]);
    }
    if (e < end) {
        const int c0 = colarr[e];
        const uint4* m0 = (const uint4*)(src + (size_t)c0 * DIM + q * 16);
        uint4 v0 = m0[0], v1 = m0[1];
        unpack_add(v0.x, a[0], a[1]);   unpack_add(v0.y, a[2], a[3]);
        unpack_add(v0.z, a[4], a[5]);   unpack_add(v0.w, a[6], a[7]);
        unpack_add(v1.x, a[8], a[9]);   unpack_add(v1.y, a[10], a[11]);
        unpack_add(v1.z, a[12], a[13]); unpack_add(v1.w, a[14], a[15]);
    }
#pragma unroll
    for (int j = 0; j < 16; ++j) a[j] *= inv;

    uint4* d = (uint4*)(dst + (size_t)gn * DIM + q * 16);
    d[0] = make_uint4(packbf(a[0], a[1]), packbf(a[2], a[3]),
                      packbf(a[4], a[5]), packbf(a[6], a[7]));
    d[1] = make_uint4(packbf(a[8], a[9]), packbf(a[10], a[11]),
                      packbf(a[12], a[13]), packbf(a[14], a[15]));
}

// ---------------- fused GEMM+GRU, minimal persistent registers ----------------
// Gate order: r -> h_n(whh) -> seed acc=bi_n+r*(h_n+bh_n) (r dies) -> i_n chain
// -> nn packed bf16 (16 regs) -> z gate -> epilogue (z straight from AGPR acc).
// Peak persistent arch state: 16 packed regs. One 32-AGPR acc block at a time.
__global__ void __launch_bounds__(256, 3)
k_gemm(const u16* __restrict__ g0, const u16* __restrict__ g1, const u16* __restrict__ g2,
       const u16* __restrict__ o0, const u16* __restrict__ o1, const u16* __restrict__ o2,
       u16* __restrict__ d0, u16* __restrict__ d1, u16* __restrict__ d2,
       const u16* __restrict__ Wf_hi, const u16* __restrict__ Wf_lo,
       const u16* __restrict__ whh_hi, const u16* __restrict__ whh_lo,
       const float* __restrict__ bih, const float* __restrict__ bhh, int layer)
{
    __shared__ u16 sA[64 * SP];   // agg (bf16) -> out staging
    __shared__ u16 sH[64 * SP];   // own h

    const int tid  = threadIdx.x;
    const int lane = tid & 63;
    const int wv   = tid >> 6;
    const int l15  = lane & 15;
    const int quad = lane >> 4;
    const int colbase = wv * 32;

    const int set  = blockIdx.x / MT;
    const int tile = blockIdx.x - set * MT;
    const int n0   = tile * 64;

    const u16* __restrict__ gsrc = (set == 0) ? g0 : (set == 1) ? g1 : g2;
    const u16* __restrict__ osrc = (set == 0) ? o0 : (set == 1) ? o1 : o2;
    u16* __restrict__ dst        = (set == 0) ? d0 : (set == 1) ? d1 : d2;
    const u16* wf_hi = Wf_hi + (size_t)(set * NLAYERS + layer) * 384 * DIM;
    const u16* wf_lo = Wf_lo + (size_t)(set * NLAYERS + layer) * 384 * DIM;
    const u16* wh_hi = whh_hi + (size_t)set * 384 * DIM;
    const u16* wh_lo = whh_lo + (size_t)set * 384 * DIM;
    const float* bi_s = bih + (size_t)set * 384;
    const float* bh_s = bhh + (size_t)set * 384;

    const int srow = tid >> 2;
    const int sq   = tid & 3;
    const int sgn  = n0 + srow;

    // ---- stage agg + own ----
    {
        uint4 va[4], vh[4];
#pragma unroll
        for (int j = 0; j < 4; ++j) { va[j] = make_uint4(0,0,0,0); vh[j] = make_uint4(0,0,0,0); }
        if (sgn < N_NODES) {
            const uint4* ga = (const uint4*)(gsrc + (size_t)sgn * DIM + sq * 32);
            const uint4* oh = (const uint4*)(osrc + (size_t)sgn * DIM + sq * 32);
#pragma unroll
            for (int j = 0; j < 4; ++j) { va[j] = ga[j]; vh[j] = oh[j]; }
        }
        uint4* da = (uint4*)&sA[srow * SP + sq * 32];
        uint4* dh = (uint4*)&sH[srow * SP + sq * 32];
#pragma unroll
        for (int j = 0; j < 4; ++j) { da[j] = va[j]; dh[j] = vh[j]; }
    }
    __syncthreads();

    uint32_t pk[4][2][2];   // persistent packed pairs: r, then nn

    // ---- r gate (agg@Wf + h@whh, hi/lo) ----
    {
        f32x4 acc[4][2];
#pragma unroll
        for (int mt = 0; mt < 4; ++mt)
#pragma unroll
            for (int nt = 0; nt < 2; ++nt) acc[mt][nt] = (f32x4){0.f, 0.f, 0.f, 0.f};
#pragma unroll
        for (int ks = 0; ks < 4; ++ks) {
            const int k0 = ks * 32;
            bf16x8 ag[4], ah[4];
#pragma unroll
            for (int mt = 0; mt < 4; ++mt) {
                ag[mt] = *(const bf16x8*)&sA[(mt * 16 + l15) * SP + k0 + quad * 8];
                ah[mt] = *(const bf16x8*)&sH[(mt * 16 + l15) * SP + k0 + quad * 8];
            }
#pragma unroll
            for (int nt = 0; nt < 2; ++nt) {
                const size_t boff = (size_t)(colbase + nt * 16 + l15) * 128 + k0 + quad * 8;
                bf16x8 fi_h = *(const bf16x8*)(wf_hi + boff);
                bf16x8 fi_l = *(const bf16x8*)(wf_lo + boff);
                bf16x8 hh_h = *(const bf16x8*)(wh_hi + boff);
                bf16x8 hh_l = *(const bf16x8*)(wh_lo + boff);
#pragma unroll
                for (int mt = 0; mt < 4; ++mt) {
                    f32x4 a2 = acc[mt][nt];
                    a2 = __builtin_amdgcn_mfma_f32_16x16x32_bf16(ag[mt], fi_h, a2, 0, 0, 0);
                    a2 = __builtin_amdgcn_mfma_f32_16x16x32_bf16(ag[mt], fi_l, a2, 0, 0, 0);
                    a2 = __builtin_amdgcn_mfma_f32_16x16x32_bf16(ah[mt], hh_h, a2, 0, 0, 0);
                    a2 = __builtin_amdgcn_mfma_f32_16x16x32_bf16(ah[mt], hh_l, a2, 0, 0, 0);
                    acc[mt][nt] = a2;
                }
            }
        }
#pragma unroll
        for (int mt = 0; mt < 4; ++mt)
#pragma unroll
            for (int nt = 0; nt < 2; ++nt) {
                const int c = colbase + nt * 16 + l15;
                const float bb = bi_s[c] + bh_s[c];
                pk[mt][nt][0] = packbf(sigmoidf_(acc[mt][nt][0] + bb),
                                       sigmoidf_(acc[mt][nt][1] + bb));
                pk[mt][nt][1] = packbf(sigmoidf_(acc[mt][nt][2] + bb),
                                       sigmoidf_(acc[mt][nt][3] + bb));
            }
    }

    // ---- h_n (whh only) -> seed -> i_n chain ----
    f32x4 acc_n[4][2];
#pragma unroll
    for (int mt = 0; mt < 4; ++mt)
#pragma unroll
        for (int nt = 0; nt < 2; ++nt) acc_n[mt][nt] = (f32x4){0.f, 0.f, 0.f, 0.f};
#pragma unroll
    for (int ks = 0; ks < 4; ++ks) {
        const int k0 = ks * 32;
        bf16x8 ah[4];
#pragma unroll
        for (int mt = 0; mt < 4; ++mt)
            ah[mt] = *(const bf16x8*)&sH[(mt * 16 + l15) * SP + k0 + quad * 8];
#pragma unroll
        for (int nt = 0; nt < 2; ++nt) {
            const size_t boff = (size_t)(256 + colbase + nt * 16 + l15) * 128 + k0 + quad * 8;
            bf16x8 hh_h = *(const bf16x8*)(wh_hi + boff);
            bf16x8 hh_l = *(const bf16x8*)(wh_lo + boff);
#pragma unroll
            for (int mt = 0; mt < 4; ++mt) {
                acc_n[mt][nt] = __builtin_amdgcn_mfma_f32_16x16x32_bf16(ah[mt], hh_h, acc_n[mt][nt], 0, 0, 0);
                acc_n[mt][nt] = __builtin_amdgcn_mfma_f32_16x16x32_bf16(ah[mt], hh_l, acc_n[mt][nt], 0, 0, 0);
            }
        }
    }
    // seed: acc = bi_n + r*(h_n + bh_n)   (r dies here)
#pragma unroll
    for (int mt = 0; mt < 4; ++mt)
#pragma unroll
        for (int nt = 0; nt < 2; ++nt) {
            const int c = colbase + nt * 16 + l15;
            const float bin = bi_s[256 + c];
            const float bhn = bh_s[256 + c];
#pragma unroll
            for (int r = 0; r < 4; ++r) {
                const float rr = unpk(pk[mt][nt][r >> 1], r & 1);
                acc_n[mt][nt][r] = bin + rr * (acc_n[mt][nt][r] + bhn);
            }
        }
#pragma unroll
    for (int ks = 0; ks < 4; ++ks) {
        const int k0 = ks * 32;
        bf16x8 ag[4];
#pragma unroll
        for (int mt = 0; mt < 4; ++mt)
            ag[mt] = *(const bf16x8*)&sA[(mt * 16 + l15) * SP + k0 + quad * 8];
#pragma unroll
        for (int nt = 0; nt < 2; ++nt) {
            const size_t boff = (size_t)(256 + colbase + nt * 16 + l15) * 128 + k0 + quad * 8;
            bf16x8 fi_h = *(const bf16x8*)(wf_hi + boff);
            bf16x8 fi_l = *(const bf16x8*)(wf_lo + boff);
#pragma unroll
            for (int mt = 0; mt < 4; ++mt) {
                acc_n[mt][nt] = __builtin_amdgcn_mfma_f32_16x16x32_bf16(ag[mt], fi_h, acc_n[mt][nt], 0, 0, 0);
                acc_n[mt][nt] = __builtin_amdgcn_mfma_f32_16x16x32_bf16(ag[mt], fi_l, acc_n[mt][nt], 0, 0, 0);
            }
        }
    }
    // nn = tanh(acc) packed (acc_n dies)
#pragma unroll
    for (int mt = 0; mt < 4; ++mt)
#pragma unroll
        for (int nt = 0; nt < 2; ++nt) {
            pk[mt][nt][0] = packbf(tanhf_(acc_n[mt][nt][0]), tanhf_(acc_n[mt][nt][1]));
            pk[mt][nt][1] = packbf(tanhf_(acc_n[mt][nt][2]), tanhf_(acc_n[mt][nt][3]));
        }

    // ---- z gate (last; lives in AGPR acc across the barrier) ----
    f32x4 acc_z[4][2];
#pragma unroll
    for (int mt = 0; mt < 4; ++mt)
#pragma unroll
        for (int nt = 0; nt < 2; ++nt) acc_z[mt][nt] = (f32x4){0.f, 0.f, 0.f, 0.f};
#pragma unroll
    for (int ks = 0; ks < 4; ++ks) {
        const int k0 = ks * 32;
        bf16x8 ag[4], ah[4];
#pragma unroll
        for (int mt = 0; mt < 4; ++mt) {
            ag[mt] = *(const bf16x8*)&sA[(mt * 16 + l15) * SP + k0 + quad * 8];
            ah[mt] = *(const bf16x8*)&sH[(mt * 16 + l15) * SP + k0 + quad * 8];
        }
#pragma unroll
        for (int nt = 0; nt < 2; ++nt) {
            const size_t boff = (size_t)(128 + colbase + nt * 16 + l15) * 128 + k0 + quad * 8;
            bf16x8 fi_h = *(const bf16x8*)(wf_hi + boff);
            bf16x8 fi_l = *(const bf16x8*)(wf_lo + boff);
            bf16x8 hh_h = *(const bf16x8*)(wh_hi + boff);
            bf16x8 hh_l = *(const bf16x8*)(wh_lo + boff);
#pragma unroll
            for (int mt = 0; mt < 4; ++mt) {
                f32x4 a2 = acc_z[mt][nt];
                a2 = __builtin_amdgcn_mfma_f32_16x16x32_bf16(ag[mt], fi_h, a2, 0, 0, 0);
                a2 = __builtin_amdgcn_mfma_f32_16x16x32_bf16(ag[mt], fi_l, a2, 0, 0, 0);
                a2 = __builtin_amdgcn_mfma_f32_16x16x32_bf16(ah[mt], hh_h, a2, 0, 0, 0);
                a2 = __builtin_amdgcn_mfma_f32_16x16x32_bf16(ah[mt], hh_l, a2, 0, 0, 0);
                acc_z[mt][nt] = a2;
            }
        }
    }

    // ---- combine -> out (bf16) into sA, then coalesced store ----
    __syncthreads();   // all waves done reading sA/sH fragments
#pragma unroll
    for (int mt = 0; mt < 4; ++mt)
#pragma unroll
        for (int nt = 0; nt < 2; ++nt) {
            const int c = colbase + nt * 16 + l15;
            const float bz = bi_s[128 + c] + bh_s[128 + c];
#pragma unroll
            for (int r = 0; r < 4; ++r) {
                const int row = mt * 16 + quad * 4 + r;
                const float zz = sigmoidf_(acc_z[mt][nt][r] + bz);
                const float nn = unpk(pk[mt][nt][r >> 1], r & 1);
                const float hv = bf2f(sH[row * SP + c]);
                sA[row * SP + c] = f2bf((1.0f - zz) * nn + zz * hv);
            }
        }
    __syncthreads();
    if (sgn < N_NODES) {
        const uint4* sp = (const uint4*)&sA[srow * SP + sq * 32];
        uint4* d = (uint4*)(dst + (size_t)sgn * DIM + sq * 32);
        d[0] = sp[0]; d[1] = sp[1]; d[2] = sp[2]; d[3] = sp[3];
    }
}

// ---------------- x = (a+b+c)/3 (bf16) ----------------
__global__ void k_avg3(const u16* __restrict__ a, const u16* __restrict__ b,
                       const u16* __restrict__ c, u16* __restrict__ d) {
    const int i = blockIdx.x * 256 + threadIdx.x;
    const uint4 va = ((const uint4*)a)[i];
    const uint4 vb = ((const uint4*)b)[i];
    const uint4 vc = ((const uint4*)c)[i];
    const float third = 1.0f / 3.0f;
    auto comb = [&](uint32_t x, uint32_t y, uint32_t z) -> uint32_t {
        float l = 0.f, h = 0.f;
        unpack_add(x, l, h); unpack_add(y, l, h); unpack_add(z, l, h);
        return packbf(l * third, h * third);
    };
    uint4 vo;
    vo.x = comb(va.x, vb.x, vc.x);
    vo.y = comb(va.y, vb.y, vc.y);
    vo.z = comb(va.z, vb.z, vc.z);
    vo.w = comb(va.w, vb.w, vc.w);
    ((uint4*)d)[i] = vo;
}

// ---------------- pooling (bf16 x) ----------------
__global__ void k_pool(const u16* __restrict__ xf, const int* __restrict__ batch,
                       float* __restrict__ pooled, int* __restrict__ gcnt) {
    const int tid = threadIdx.x;
    const int f = tid & 127;
    const int half = tid >> 7;
    const int nstart = blockIdx.x * 64 + half * 32;
    float accv = 0.0f;
    int curg = -1, cnt = 0;
    for (int t = 0; t < 32; ++t) {
        const int n = nstart + t;
        if (n >= N_NODES) break;
        const int g = batch[n];
        if (g != curg) {
            if (curg >= 0) {
                atomicAdd(&pooled[curg * DIM + f], accv);
                if (f == 0) atomicAdd(&gcnt[curg], cnt);
            }
            curg = g; accv = 0.0f; cnt = 0;
        }
        accv += bf2f(xf[(size_t)n * DIM + f]);
        cnt++;
    }
    if (curg >= 0) {
        atomicAdd(&pooled[curg * DIM + f], accv);
        if (f == 0) atomicAdd(&gcnt[curg], cnt);
    }
}

// ---------------- MLP head ----------------
__global__ void k_head(const float* __restrict__ pooled, const int* __restrict__ gcnt,
                       const float* __restrict__ ptf,
                       const float* __restrict__ fc1w, const float* __restrict__ fc1b,
                       const float* __restrict__ fc2w, const float* __restrict__ fc2b,
                       const float* __restrict__ fclw, const float* __restrict__ fclb,
                       void* __restrict__ out, const int* __restrict__ flag) {
    __shared__ float xh[64 * 129];
    __shared__ float h1[64 * 80];
    const int tid = threadIdx.x;
    for (int i = tid; i < 64 * 128; i += 256) {
        const int g = i >> 7;
        int c = gcnt[g]; if (c < 1) c = 1;
        xh[g * 129 + (i & 127)] = pooled[i] / (float)c;
    }
    for (int g = tid; g < 64; g += 256) xh[g * 129 + 128] = ptf[g];
    __syncthreads();
    for (int i = tid; i < 64 * 80; i += 256) {
        const int g = i / 80, c = i - g * 80;
        float s = fc1b[c];
        const float* xr = &xh[g * 129];
        const float* wr = &fc1w[c * 129];
        for (int k = 0; k < 129; ++k) s += xr[k] * wr[k];
        h1[i] = (s > 0.0f) ? s : 0.01f * s;
    }
    __syncthreads();
    float* h2 = xh;
    for (int i = tid; i < 64 * 80; i += 256) {
        const int g = i / 80, c = i - g * 80;
        float s = fc2b[c];
        const float* hr = &h1[g * 80];
        const float* wr = &fc2w[c * 80];
        for (int k = 0; k < 80; ++k) s += hr[k] * wr[k];
        h2[i] = (s > 0.0f) ? s : 0.01f * s;
    }
    __syncthreads();
    for (int i = tid; i < 128; i += 256) {
        const int g = i >> 1, c = i & 1;
        float s = fclb[c];
        const float* hr = &h2[g * 80];
        const float* wr = &fclw[c * 80];
        for (int k = 0; k < 80; ++k) s += hr[k] * wr[k];
        if (*flag) ((u16*)out)[i] = f2bf(s);
        else       ((float*)out)[i] = s;
    }
}

// ---------------- launcher ----------------
extern "C" void kernel_launch(void* const* d_in, const int* in_sizes, int n_in,
                              void* d_out, int out_size, void* d_ws, size_t ws_size,
                              hipStream_t stream) {
    if (n_in < 16) return;
    const void* x_in    = d_in[0];
    const int*  ei      = (const int*)d_in[1];
    const int*  attr    = (const int*)d_in[2];
    const int*  batch   = (const int*)d_in[3];
    const void* pt_in   = d_in[4];
    const void* W_in    = d_in[5];
    const void* wih_in  = d_in[6];
    const void* whh_in  = d_in[7];
    const void* bih_in  = d_in[8];
    const void* bhh_in  = d_in[9];
    const void* fc1w_in = d_in[10];
    const void* fc1b_in = d_in[11];
    const void* fc2w_in = d_in[12];
    const void* fc2b_in = d_in[13];
    const void* fclw_in = d_in[14];
    const void* fclb_in = d_in[15];

    char* ws = (char*)d_ws;
    size_t o = 0;
    auto alloc = [&](size_t b) { size_t r = o; o += (b + 255) & ~(size_t)255; return r; };

    const size_t NB2 = (size_t)N_NODES * DIM * 2;
    const size_t o_flag   = alloc(4);
    const size_t o_xbf    = alloc(NB2);
    const size_t o_A0     = alloc(NB2);
    const size_t o_A1     = alloc(NB2);
    const size_t o_A2     = alloc(NB2);
    const size_t o_B0     = alloc(NB2);
    const size_t o_B1     = alloc(NB2);
    const size_t o_Wt     = alloc((size_t)NSETS * NLAYERS * DIM * DIM * 4);
    const size_t o_Wf_hi  = alloc((size_t)NSETS * NLAYERS * 384 * DIM * 2);
    const size_t o_Wf_lo  = alloc((size_t)NSETS * NLAYERS * 384 * DIM * 2);
    const size_t o_whh_hi = alloc((size_t)NSETS * 384 * DIM * 2);
    const size_t o_whh_lo = alloc((size_t)NSETS * 384 * DIM * 2);
    const size_t o_bih    = alloc((size_t)NSETS * 384 * 4);
    const size_t o_bhh    = alloc((size_t)NSETS * 384 * 4);
    const size_t o_fc1w   = alloc(10320 * 4);
    const size_t o_fc1b   = alloc(80 * 4);
    const size_t o_fc2w   = alloc(6400 * 4);
    const size_t o_fc2b   = alloc(80 * 4);
    const size_t o_fclw   = alloc(160 * 4);
    const size_t o_fclb   = alloc(2 * 4);
    const size_t o_ptf    = alloc(64 * 4);
    const size_t o_cnt    = alloc(((size_t)3 * N_NODES + 1) * 4);
    const size_t o_cursor = alloc((size_t)3 * N_NODES * 4);
    const size_t o_col    = alloc((size_t)N_EDGES * 4);
    const int    nb_scan  = (3 * N_NODES + 1023) / 1024;
    const size_t o_part   = alloc((size_t)nb_scan * 4);
    const size_t o_pooled = alloc((size_t)NGRAPH * DIM * 4);
    const size_t o_gcnt   = alloc((size_t)NGRAPH * 4);

    if (ws_size < o) {
        fprintf(stderr, "GGNN kernel: workspace too small: need %zu, have %zu\n", o, ws_size);
        return;
    }

    int*   flag   = (int*)(ws + o_flag);
    u16*   xbf    = (u16*)(ws + o_xbf);
    u16*   A0     = (u16*)(ws + o_A0);
    u16*   A1     = (u16*)(ws + o_A1);
    u16*   A2     = (u16*)(ws + o_A2);
    u16*   B0     = (u16*)(ws + o_B0);
    u16*   B1     = (u16*)(ws + o_B1);
    float* Wt     = (float*)(ws + o_Wt);
    u16*   Wf_hi  = (u16*)(ws + o_Wf_hi);
    u16*   Wf_lo  = (u16*)(ws + o_Wf_lo);
    u16*   whh_hi = (u16*)(ws + o_whh_hi);
    u16*   whh_lo = (u16*)(ws + o_whh_lo);
    float* bihf   = (float*)(ws + o_bih);
    float* bhhf   = (float*)(ws + o_bhh);
    float* fc1wf  = (float*)(ws + o_fc1w);
    float* fc1bf  = (float*)(ws + o_fc1b);
    float* fc2wf  = (float*)(ws + o_fc2w);
    float* fc2bf  = (float*)(ws + o_fc2b);
    float* fclwf  = (float*)(ws + o_fclw);
    float* fclbf  = (float*)(ws + o_fclb);
    float* ptf    = (float*)(ws + o_ptf);
    int*   cnt    = (int*)(ws + o_cnt);
    int*   rp     = cnt;
    int*   cursor = (int*)(ws + o_cursor);
    int*   col    = (int*)(ws + o_col);
    int*   part   = (int*)(ws + o_part);
    float* pooled = (float*)(ws + o_pooled);
    int*   gcnt   = (int*)(ws + o_gcnt);

    hipMemsetAsync(cnt, 0, (size_t)3 * N_NODES * 4, stream);
    hipMemsetAsync(pooled, 0, (o_gcnt - o_pooled) + (size_t)NGRAPH * 4, stream);

    k_detect<<<1, 256, 0, stream>>>((const u16*)x_in, flag);

    // converts + weight prep
    k_to_bf<<<(N_NODES * DIM + 2047) / 2048, 256, 0, stream>>>(x_in, xbf, N_NODES * DIM, flag);
    k_transW<<<(NSETS * NLAYERS * DIM * DIM + 255) / 256, 256, 0, stream>>>(W_in, Wt, flag);
    k_fuse<<<(NSETS * NLAYERS * 384 * DIM) / 256, 256, 0, stream>>>(Wt, wih_in, Wf_hi, Wf_lo, flag);
    k_prep_G<<<(NSETS * 384 * DIM + 255) / 256, 256, 0, stream>>>(whh_in, whh_hi, whh_lo, flag);
    k_convert<<<(NSETS * 384 + 255) / 256, 256, 0, stream>>>(bih_in, bihf, NSETS * 384, flag);
    k_convert<<<(NSETS * 384 + 255) / 256, 256, 0, stream>>>(bhh_in, bhhf, NSETS * 384, flag);
    k_convert<<<(10320 + 255) / 256, 256, 0, stream>>>(fc1w_in, fc1wf, 10320, flag);
    k_convert<<<1, 256, 0, stream>>>(fc1b_in, fc1bf, 80, flag);
    k_convert<<<(6400 + 255) / 256, 256, 0, stream>>>(fc2w_in, fc2wf, 6400, flag);
    k_convert<<<1, 256, 0, stream>>>(fc2b_in, fc2bf, 80, flag);
    k_convert<<<1, 256, 0, stream>>>(fclw_in, fclwf, 160, flag);
    k_convert<<<1, 256, 0, stream>>>(fclb_in, fclbf, 2, flag);
    k_convert<<<1, 256, 0, stream>>>(pt_in, ptf, 64, flag);

    // CSR build
    k_deg<<<(N_EDGES + 255) / 256, 256, 0, stream>>>(ei, attr, cnt);
    k_scan1<<<nb_scan, 1024, 0, stream>>>(cnt, rp, part, 3 * N_NODES);
    k_scan2<<<1, 1024, 0, stream>>>(part, nb_scan);
    k_scan3<<<nb_scan, 1024, 0, stream>>>(rp, cursor, part, 3 * N_NODES);
    k_fill<<<(N_EDGES + 255) / 256, 256, 0, stream>>>(ei, attr, cursor, col);

    // GGC passes
    for (int pass = 0; pass < NPASS; ++pass) {
        k_gather<<<3 * GT, 256, 0, stream>>>(xbf, xbf, xbf, A0, A1, A2, rp, col);
        k_gemm<<<3 * MT, 256, 0, stream>>>(A0, A1, A2, xbf, xbf, xbf, A0, A1, A2,
                                           Wf_hi, Wf_lo, whh_hi, whh_lo, bihf, bhhf, 0);
        k_gather<<<3 * GT, 256, 0, stream>>>(A0, A1, A2, B0, B1, xbf, rp, col);
        k_gemm<<<3 * MT, 256, 0, stream>>>(B0, B1, xbf, A0, A1, A2, A0, A1, A2,
                                           Wf_hi, Wf_lo, whh_hi, whh_lo, bihf, bhhf, 1);
        k_avg3<<<(N_NODES * DIM / 8) / 256, 256, 0, stream>>>(A0, A1, A2, xbf);
    }

    // pooling + head
    k_pool<<<MT, 256, 0, stream>>>(xbf, batch, pooled, gcnt);
    k_head<<<1, 256, 0, stream>>>(pooled, gcnt, ptf, fc1wf, fc1bf, fc2wf, fc2bf,
                                  fclwf, fclbf, d_out, flag);
}

// Round 9
// 1597.312 us; speedup vs baseline: 1.1645x; 1.1645x over previous
//
#include <hip/hip_runtime.h>
#include <cstdio>
#include <cstdint>

#define N_NODES 100000
#define N_EDGES 600000
#define DIM     128
#define NSETS   3
#define NLAYERS 2
#define NGRAPH  64
#define NPASS   2
#define SP      136       // LDS row stride in shorts
#define GT      3125      // gather tiles (32 nodes each)
#define MT      1563      // gemm tiles (64 nodes each)

typedef __bf16 bf16x8 __attribute__((ext_vector_type(8)));
typedef float  f32x4  __attribute__((ext_vector_type(4)));
typedef unsigned short u16;

static __device__ __forceinline__ float bf2f(u16 u) {
    return __uint_as_float(((uint32_t)u) << 16);
}
static __device__ __forceinline__ u16 f2bf(float f) {
    uint32_t u = __float_as_uint(f);
    uint32_t r = (u + 0x7FFFu + ((u >> 16) & 1u)) >> 16;
    return (u16)r;
}
static __device__ __forceinline__ uint32_t packbf(float lo, float hi) {
    return (uint32_t)f2bf(lo) | ((uint32_t)f2bf(hi) << 16);
}
static __device__ __forceinline__ void unpack_add(uint32_t u, float& a0, float& a1) {
    a0 += __uint_as_float(u << 16);
    a1 += __uint_as_float(u & 0xFFFF0000u);
}
static __device__ __forceinline__ float sigmoidf_(float x) {
    return 1.0f / (1.0f + __expf(-x));
}
static __device__ __forceinline__ float tanhf_(float x) {
    return 1.0f - 2.0f / (__expf(2.0f * x) + 1.0f);
}

// ---------------- dtype detection ----------------
__global__ void k_detect(const u16* __restrict__ x, int* __restrict__ flag) {
    __shared__ float red[256];
    float m = 0.0f;
    for (int i = threadIdx.x; i < 8192; i += 256) {
        float f = __uint_as_float(((uint32_t)x[i]) << 16);
        f = fabsf(f);
        if (isnan(f)) f = 3.0e38f;
        m = fmaxf(m, f);
    }
    red[threadIdx.x] = m;
    __syncthreads();
    for (int off = 128; off > 0; off >>= 1) {
        if (threadIdx.x < off) red[threadIdx.x] = fmaxf(red[threadIdx.x], red[threadIdx.x + off]);
        __syncthreads();
    }
    if (threadIdx.x == 0) flag[0] = (red[0] < 1.0e6f) ? 1 : 0;
}

// ---------------- converts ----------------
__global__ void k_convert(const void* __restrict__ src, float* __restrict__ dst,
                          int n, const int* __restrict__ flag) {
    const int f = *flag;
    for (int i = blockIdx.x * blockDim.x + threadIdx.x; i < n; i += gridDim.x * blockDim.x) {
        float v;
        if (f) v = bf2f(((const u16*)src)[i]);
        else   v = ((const float*)src)[i];
        dst[i] = v;
    }
}

__global__ void k_to_bf(const void* __restrict__ src, u16* __restrict__ dst,
                        int n, const int* __restrict__ flag) {
    const int f = *flag;
    for (int i = blockIdx.x * blockDim.x + threadIdx.x; i < n; i += gridDim.x * blockDim.x) {
        if (f) dst[i] = ((const u16*)src)[i];
        else   dst[i] = f2bf(((const float*)src)[i]);
    }
}

// W raw [S][L][j][d] -> Wt fp32 [sl][d][j]
__global__ void k_transW(const void* __restrict__ src, float* __restrict__ dst,
                         const int* __restrict__ flag) {
    const int total = NSETS * NLAYERS * DIM * DIM;
    const int f = *flag;
    for (int i = blockIdx.x * blockDim.x + threadIdx.x; i < total; i += gridDim.x * blockDim.x) {
        const int sl = i >> 14;
        const int rem = i & 16383;
        const int d = rem >> 7;
        const int j = rem & 127;
        const int si = (sl << 14) + j * 128 + d;
        float v;
        if (f) v = bf2f(((const u16*)src)[si]);
        else   v = ((const float*)src)[si];
        dst[i] = v;
    }
}

// Wf[sl][n][j] = sum_d wih[s][n][d] * Wt[sl][d][j]
__global__ void k_fuse(const float* __restrict__ Wt, const void* __restrict__ wih_raw,
                       u16* __restrict__ hi, u16* __restrict__ lo,
                       const int* __restrict__ flag) {
    const int f = *flag;
    const int i = blockIdx.x * 256 + threadIdx.x;
    const int sl = i / 49152;
    const int rem = i - sl * 49152;
    const int n = rem >> 7;
    const int j = rem & 127;
    const int s = sl >> 1;
    const float* wt = Wt + (sl << 14) + j;
    const int wb = (s * 384 + n) * 128;
    float acc = 0.0f;
#pragma unroll 8
    for (int d = 0; d < 128; ++d) {
        float wv;
        if (f) wv = bf2f(((const u16*)wih_raw)[wb + d]);
        else   wv = ((const float*)wih_raw)[wb + d];
        acc = fmaf(wv, wt[d * 128], acc);
    }
    u16 h = f2bf(acc);
    hi[i] = h;
    lo[i] = f2bf(acc - bf2f(h));
}

// whh: [S][384][128] -> hi/lo bf16
__global__ void k_prep_G(const void* __restrict__ src, u16* __restrict__ hi,
                         u16* __restrict__ lo, const int* __restrict__ flag) {
    const int total = NSETS * 384 * DIM;
    const int f = *flag;
    for (int i = blockIdx.x * blockDim.x + threadIdx.x; i < total; i += gridDim.x * blockDim.x) {
        float v;
        if (f) v = bf2f(((const u16*)src)[i]);
        else   v = ((const float*)src)[i];
        u16 h = f2bf(v);
        hi[i] = h;
        lo[i] = f2bf(v - bf2f(h));
    }
}

// ---------------- CSR build ----------------
__global__ void k_deg(const int* __restrict__ ei, const int* __restrict__ attr,
                      int* __restrict__ cnt) {
    int e = blockIdx.x * 256 + threadIdx.x;
    if (e < N_EDGES) {
        int t = attr[e];
        int d = ei[N_EDGES + e];
        atomicAdd(&cnt[t * N_NODES + d], 1);
    }
}

__global__ void k_scan1(const int* __restrict__ cnt, int* __restrict__ rp,
                        int* __restrict__ part, int n) {
    __shared__ int buf[1024];
    int gid = blockIdx.x * 1024 + threadIdx.x;
    int v = (gid < n) ? cnt[gid] : 0;
    buf[threadIdx.x] = v;
    __syncthreads();
    for (int off = 1; off < 1024; off <<= 1) {
        int t = (threadIdx.x >= off) ? buf[threadIdx.x - off] : 0;
        __syncthreads();
        buf[threadIdx.x] += t;
        __syncthreads();
    }
    if (gid < n) rp[gid] = buf[threadIdx.x] - v;
    if (threadIdx.x == 1023) part[blockIdx.x] = buf[1023];
}

__global__ void k_scan2(int* __restrict__ part, int nb) {
    __shared__ int buf[1024];
    int v = (threadIdx.x < nb) ? part[threadIdx.x] : 0;
    buf[threadIdx.x] = v;
    __syncthreads();
    for (int off = 1; off < 1024; off <<= 1) {
        int t = (threadIdx.x >= off) ? buf[threadIdx.x - off] : 0;
        __syncthreads();
        buf[threadIdx.x] += t;
        __syncthreads();
    }
    if (threadIdx.x < nb) part[threadIdx.x] = buf[threadIdx.x] - v;
}

__global__ void k_scan3(int* __restrict__ rp, int* __restrict__ cursor,
                        const int* __restrict__ part, int n) {
    int gid = blockIdx.x * 1024 + threadIdx.x;
    if (gid < n) {
        int v = rp[gid] + part[blockIdx.x];
        rp[gid] = v;
        cursor[gid] = v;
    }
    if (gid == 0) rp[n] = N_EDGES;
}

__global__ void k_fill(const int* __restrict__ ei, const int* __restrict__ attr,
                       int* __restrict__ cursor, int* __restrict__ col) {
    int e = blockIdx.x * 256 + threadIdx.x;
    if (e < N_EDGES) {
        int t = attr[e];
        int d = ei[N_EDGES + e];
        int s = ei[e];
        int pos = atomicAdd(&cursor[t * N_NODES + d], 1);
        col[pos] = s;
    }
}

// ---------------- gather ----------------
__global__ void __launch_bounds__(256, 6)
k_gather(const u16* __restrict__ s0, const u16* __restrict__ s1, const u16* __restrict__ s2,
         u16* __restrict__ d0, u16* __restrict__ d1, u16* __restrict__ d2,
         const int* __restrict__ rp, const int* __restrict__ colarr) {
    const int bx = blockIdx.x;
    const int set = bx / GT;
    const int tile = bx - set * GT;
    const u16* __restrict__ src = (set == 0) ? s0 : (set == 1) ? s1 : s2;
    u16* __restrict__ dst = (set == 0) ? d0 : (set == 1) ? d1 : d2;
    const int* __restrict__ rp_s = rp + set * N_NODES;

    const int nl = threadIdx.x >> 3;
    const int q  = threadIdx.x & 7;
    const int gn = tile * 32 + nl;

    float a[16];
#pragma unroll
    for (int j = 0; j < 16; ++j) a[j] = 0.0f;

    const int beg = rp_s[gn], end = rp_s[gn + 1];
    int dg = end - beg; if (dg < 1) dg = 1;
    const float inv = 1.0f / (float)dg;

    int e = beg;
    for (; e + 2 <= end; e += 2) {
        const int c0 = colarr[e];
        const int c1 = colarr[e + 1];
        const uint4* m0 = (const uint4*)(src + (size_t)c0 * DIM + q * 16);
        const uint4* m1 = (const uint4*)(src + (size_t)c1 * DIM + q * 16);
        uint4 v0 = m0[0], v1 = m0[1], w0 = m1[0], w1 = m1[1];
        unpack_add(v0.x, a[0], a[1]);   unpack_add(v0.y, a[2], a[3]);
        unpack_add(v0.z, a[4], a[5]);   unpack_add(v0.w, a[6], a[7]);
        unpack_add(v1.x, a[8], a[9]);   unpack_add(v1.y, a[10], a[11]);
        unpack_add(v1.z, a[12], a[13]); unpack_add(v1.w, a[14], a[15]);
        unpack_add(w0.x, a[0], a[1]);   unpack_add(w0.y, a[2], a[3]);
        unpack_add(w0.z, a[4], a[5]);   unpack_add(w0.w, a[6], a[7]);
        unpack_add(w1.x, a[8], a[9]);   unpack_add(w1.y, a[10], a[11]);
        unpack_add(w1.z, a[12], a[13]); unpack_add(w1.w, a[14], a[15]);
    }
    if (e < end) {
        const int c0 = colarr[e];
        const uint4* m0 = (const uint4*)(src + (size_t)c0 * DIM + q * 16);
        uint4 v0 = m0[0], v1 = m0[1];
        unpack_add(v0.x, a[0], a[1]);   unpack_add(v0.y, a[2], a[3]);
        unpack_add(v0.z, a[4], a[5]);   unpack_add(v0.w, a[6], a[7]);
        unpack_add(v1.x, a[8], a[9]);   unpack_add(v1.y, a[10], a[11]);
        unpack_add(v1.z, a[12], a[13]); unpack_add(v1.w, a[14], a[15]);
    }
#pragma unroll
    for (int j = 0; j < 16; ++j) a[j] *= inv;

    uint4* d = (uint4*)(dst + (size_t)gn * DIM + q * 16);
    d[0] = make_uint4(packbf(a[0], a[1]), packbf(a[2], a[3]),
                      packbf(a[4], a[5]), packbf(a[6], a[7]));
    d[1] = make_uint4(packbf(a[8], a[9]), packbf(a[10], a[11]),
                      packbf(a[12], a[13]), packbf(a[14], a[15]));
}

// ---------------- fused GEMM+GRU: 512 threads, 16 cols/wave ----------------
// 8 waves per block; wave wv owns cols [wv*16, wv*16+16). Halved per-wave
// register demand vs 32-col layout -> fits 4 waves/SIMD (launch_bounds(512,4),
// 128-reg budget) with NO spill. Gate order: r, z (packed bf16), then n.
__global__ void __launch_bounds__(512, 4)
k_gemm(const u16* __restrict__ g0, const u16* __restrict__ g1, const u16* __restrict__ g2,
       const u16* __restrict__ o0, const u16* __restrict__ o1, const u16* __restrict__ o2,
       u16* __restrict__ d0, u16* __restrict__ d1, u16* __restrict__ d2,
       const u16* __restrict__ Wf_hi, const u16* __restrict__ Wf_lo,
       const u16* __restrict__ whh_hi, const u16* __restrict__ whh_lo,
       const float* __restrict__ bih, const float* __restrict__ bhh, int layer)
{
    __shared__ u16 sA[64 * SP];   // agg (bf16) -> out staging
    __shared__ u16 sH[64 * SP];   // own h

    const int tid  = threadIdx.x;
    const int lane = tid & 63;
    const int wv   = tid >> 6;        // 0..7
    const int l15  = lane & 15;
    const int quad = lane >> 4;
    const int col  = wv * 16 + l15;   // this lane's output column

    const int set  = blockIdx.x / MT;
    const int tile = blockIdx.x - set * MT;
    const int n0   = tile * 64;

    const u16* __restrict__ gsrc = (set == 0) ? g0 : (set == 1) ? g1 : g2;
    const u16* __restrict__ osrc = (set == 0) ? o0 : (set == 1) ? o1 : o2;
    u16* __restrict__ dst        = (set == 0) ? d0 : (set == 1) ? d1 : d2;
    const u16* wf_hi = Wf_hi + (size_t)(set * NLAYERS + layer) * 384 * DIM;
    const u16* wf_lo = Wf_lo + (size_t)(set * NLAYERS + layer) * 384 * DIM;
    const u16* wh_hi = whh_hi + (size_t)set * 384 * DIM;
    const u16* wh_lo = whh_lo + (size_t)set * 384 * DIM;
    const float* bi_s = bih + (size_t)set * 384;
    const float* bh_s = bhh + (size_t)set * 384;

    // staging coords: 64 rows x 8 chunks of 16 u16 (32 B)
    const int srow = tid >> 3;
    const int sq   = tid & 7;
    const int sgn  = n0 + srow;

    // ---- stage agg + own ----
    {
        uint4 va0 = {0,0,0,0}, va1 = {0,0,0,0}, vh0 = {0,0,0,0}, vh1 = {0,0,0,0};
        if (sgn < N_NODES) {
            const uint4* ga = (const uint4*)(gsrc + (size_t)sgn * DIM + sq * 16);
            const uint4* oh = (const uint4*)(osrc + (size_t)sgn * DIM + sq * 16);
            va0 = ga[0]; va1 = ga[1]; vh0 = oh[0]; vh1 = oh[1];
        }
        uint4* da = (uint4*)&sA[srow * SP + sq * 16];
        uint4* dh = (uint4*)&sH[srow * SP + sq * 16];
        da[0] = va0; da[1] = va1; dh[0] = vh0; dh[1] = vh1;
    }
    __syncthreads();

    // biases for this lane's column
    const float b_r = bi_s[col] + bh_s[col];
    const float b_z = bi_s[128 + col] + bh_s[128 + col];
    const float bin = bi_s[256 + col];
    const float bhn = bh_s[256 + col];

    uint32_t rz[4][4];   // [mt][r]: low16 = r, high16 = z (bf16)

    // ---- r and z gates ----
#pragma unroll
    for (int g = 0; g < 2; ++g) {
        f32x4 acc[4];
#pragma unroll
        for (int mt = 0; mt < 4; ++mt) acc[mt] = (f32x4){0.f, 0.f, 0.f, 0.f};
#pragma unroll
        for (int ks = 0; ks < 4; ++ks) {
            const int k0 = ks * 32;
            bf16x8 ag[4], ah[4];
#pragma unroll
            for (int mt = 0; mt < 4; ++mt) {
                ag[mt] = *(const bf16x8*)&sA[(mt * 16 + l15) * SP + k0 + quad * 8];
                ah[mt] = *(const bf16x8*)&sH[(mt * 16 + l15) * SP + k0 + quad * 8];
            }
            const size_t boff = (size_t)(g * 128 + col) * 128 + k0 + quad * 8;
            bf16x8 fi_h = *(const bf16x8*)(wf_hi + boff);
            bf16x8 fi_l = *(const bf16x8*)(wf_lo + boff);
            bf16x8 hh_h = *(const bf16x8*)(wh_hi + boff);
            bf16x8 hh_l = *(const bf16x8*)(wh_lo + boff);
#pragma unroll
            for (int mt = 0; mt < 4; ++mt) {
                f32x4 a2 = acc[mt];
                a2 = __builtin_amdgcn_mfma_f32_16x16x32_bf16(ag[mt], fi_h, a2, 0, 0, 0);
                a2 = __builtin_amdgcn_mfma_f32_16x16x32_bf16(ag[mt], fi_l, a2, 0, 0, 0);
                a2 = __builtin_amdgcn_mfma_f32_16x16x32_bf16(ah[mt], hh_h, a2, 0, 0, 0);
                a2 = __builtin_amdgcn_mfma_f32_16x16x32_bf16(ah[mt], hh_l, a2, 0, 0, 0);
                acc[mt] = a2;
            }
        }
        const float bb = (g == 0) ? b_r : b_z;
#pragma unroll
        for (int mt = 0; mt < 4; ++mt)
#pragma unroll
            for (int r = 0; r < 4; ++r) {
                const uint32_t v = (uint32_t)f2bf(sigmoidf_(acc[mt][r] + bb));
                if (g == 0) rz[mt][r] = v;
                else        rz[mt][r] |= v << 16;
            }
    }

    // ---- n gate: separate i/h accumulators ----
    f32x4 acc_i[4], acc_h[4];
#pragma unroll
    for (int mt = 0; mt < 4; ++mt) {
        acc_i[mt] = (f32x4){0.f, 0.f, 0.f, 0.f};
        acc_h[mt] = (f32x4){0.f, 0.f, 0.f, 0.f};
    }
#pragma unroll
    for (int ks = 0; ks < 4; ++ks) {
        const int k0 = ks * 32;
        bf16x8 ag[4], ah[4];
#pragma unroll
        for (int mt = 0; mt < 4; ++mt) {
            ag[mt] = *(const bf16x8*)&sA[(mt * 16 + l15) * SP + k0 + quad * 8];
            ah[mt] = *(const bf16x8*)&sH[(mt * 16 + l15) * SP + k0 + quad * 8];
        }
        const size_t boff = (size_t)(256 + col) * 128 + k0 + quad * 8;
        bf16x8 fi_h = *(const bf16x8*)(wf_hi + boff);
        bf16x8 fi_l = *(const bf16x8*)(wf_lo + boff);
        bf16x8 hh_h = *(const bf16x8*)(wh_hi + boff);
        bf16x8 hh_l = *(const bf16x8*)(wh_lo + boff);
#pragma unroll
        for (int mt = 0; mt < 4; ++mt) {
            acc_i[mt] = __builtin_amdgcn_mfma_f32_16x16x32_bf16(ag[mt], fi_h, acc_i[mt], 0, 0, 0);
            acc_i[mt] = __builtin_amdgcn_mfma_f32_16x16x32_bf16(ag[mt], fi_l, acc_i[mt], 0, 0, 0);
            acc_h[mt] = __builtin_amdgcn_mfma_f32_16x16x32_bf16(ah[mt], hh_h, acc_h[mt], 0, 0, 0);
            acc_h[mt] = __builtin_amdgcn_mfma_f32_16x16x32_bf16(ah[mt], hh_l, acc_h[mt], 0, 0, 0);
        }
    }

    // ---- combine -> out (bf16) into sA, then coalesced store ----
    __syncthreads();   // all waves done reading sA/sH fragments
#pragma unroll
    for (int mt = 0; mt < 4; ++mt)
#pragma unroll
        for (int r = 0; r < 4; ++r) {
            const int row = mt * 16 + quad * 4 + r;
            const float i_n = acc_i[mt][r] + bin;
            const float h_n = acc_h[mt][r] + bhn;
            const uint32_t p = rz[mt][r];
            const float rr = bf2f((u16)(p & 0xFFFFu));
            const float zz = bf2f((u16)(p >> 16));
            const float nn = tanhf_(i_n + rr * h_n);
            const float hv = bf2f(sH[row * SP + col]);
            sA[row * SP + col] = f2bf((1.0f - zz) * nn + zz * hv);
        }
    __syncthreads();
    if (sgn < N_NODES) {
        const uint4* sp = (const uint4*)&sA[srow * SP + sq * 16];
        uint4* d = (uint4*)(dst + (size_t)sgn * DIM + sq * 16);
        d[0] = sp[0]; d[1] = sp[1];
    }
}

// ---------------- x = (a+b+c)/3 (bf16) ----------------
__global__ void k_avg3(const u16* __restrict__ a, const u16* __restrict__ b,
                       const u16* __restrict__ c, u16* __restrict__ d) {
    const int i = blockIdx.x * 256 + threadIdx.x;
    const uint4 va = ((const uint4*)a)[i];
    const uint4 vb = ((const uint4*)b)[i];
    const uint4 vc = ((const uint4*)c)[i];
    const float third = 1.0f / 3.0f;
    auto comb = [&](uint32_t x, uint32_t y, uint32_t z) -> uint32_t {
        float l = 0.f, h = 0.f;
        unpack_add(x, l, h); unpack_add(y, l, h); unpack_add(z, l, h);
        return packbf(l * third, h * third);
    };
    uint4 vo;
    vo.x = comb(va.x, vb.x, vc.x);
    vo.y = comb(va.y, vb.y, vc.y);
    vo.z = comb(va.z, vb.z, vc.z);
    vo.w = comb(va.w, vb.w, vc.w);
    ((uint4*)d)[i] = vo;
}

// ---------------- pooling (bf16 x) ----------------
__global__ void k_pool(const u16* __restrict__ xf, const int* __restrict__ batch,
                       float* __restrict__ pooled, int* __restrict__ gcnt) {
    const int tid = threadIdx.x;
    const int f = tid & 127;
    const int half = tid >> 7;
    const int nstart = blockIdx.x * 64 + half * 32;
    float accv = 0.0f;
    int curg = -1, cnt = 0;
    for (int t = 0; t < 32; ++t) {
        const int n = nstart + t;
        if (n >= N_NODES) break;
        const int g = batch[n];
        if (g != curg) {
            if (curg >= 0) {
                atomicAdd(&pooled[curg * DIM + f], accv);
                if (f == 0) atomicAdd(&gcnt[curg], cnt);
            }
            curg = g; accv = 0.0f; cnt = 0;
        }
        accv += bf2f(xf[(size_t)n * DIM + f]);
        cnt++;
    }
    if (curg >= 0) {
        atomicAdd(&pooled[curg * DIM + f], accv);
        if (f == 0) atomicAdd(&gcnt[curg], cnt);
    }
}

// ---------------- MLP head ----------------
__global__ void k_head(const float* __restrict__ pooled, const int* __restrict__ gcnt,
                       const float* __restrict__ ptf,
                       const float* __restrict__ fc1w, const float* __restrict__ fc1b,
                       const float* __restrict__ fc2w, const float* __restrict__ fc2b,
                       const float* __restrict__ fclw, const float* __restrict__ fclb,
                       void* __restrict__ out, const int* __restrict__ flag) {
    __shared__ float xh[64 * 129];
    __shared__ float h1[64 * 80];
    const int tid = threadIdx.x;
    for (int i = tid; i < 64 * 128; i += 256) {
        const int g = i >> 7;
        int c = gcnt[g]; if (c < 1) c = 1;
        xh[g * 129 + (i & 127)] = pooled[i] / (float)c;
    }
    for (int g = tid; g < 64; g += 256) xh[g * 129 + 128] = ptf[g];
    __syncthreads();
    for (int i = tid; i < 64 * 80; i += 256) {
        const int g = i / 80, c = i - g * 80;
        float s = fc1b[c];
        const float* xr = &xh[g * 129];
        const float* wr = &fc1w[c * 129];
        for (int k = 0; k < 129; ++k) s += xr[k] * wr[k];
        h1[i] = (s > 0.0f) ? s : 0.01f * s;
    }
    __syncthreads();
    float* h2 = xh;
    for (int i = tid; i < 64 * 80; i += 256) {
        const int g = i / 80, c = i - g * 80;
        float s = fc2b[c];
        const float* hr = &h1[g * 80];
        const float* wr = &fc2w[c * 80];
        for (int k = 0; k < 80; ++k) s += hr[k] * wr[k];
        h2[i] = (s > 0.0f) ? s : 0.01f * s;
    }
    __syncthreads();
    for (int i = tid; i < 128; i += 256) {
        const int g = i >> 1, c = i & 1;
        float s = fclb[c];
        const float* hr = &h2[g * 80];
        const float* wr = &fclw[c * 80];
        for (int k = 0; k < 80; ++k) s += hr[k] * wr[k];
        if (*flag) ((u16*)out)[i] = f2bf(s);
        else       ((float*)out)[i] = s;
    }
}

// ---------------- launcher ----------------
extern "C" void kernel_launch(void* const* d_in, const int* in_sizes, int n_in,
                              void* d_out, int out_size, void* d_ws, size_t ws_size,
                              hipStream_t stream) {
    if (n_in < 16) return;
    const void* x_in    = d_in[0];
    const int*  ei      = (const int*)d_in[1];
    const int*  attr    = (const int*)d_in[2];
    const int*  batch   = (const int*)d_in[3];
    const void* pt_in   = d_in[4];
    const void* W_in    = d_in[5];
    const void* wih_in  = d_in[6];
    const void* whh_in  = d_in[7];
    const void* bih_in  = d_in[8];
    const void* bhh_in  = d_in[9];
    const void* fc1w_in = d_in[10];
    const void* fc1b_in = d_in[11];
    const void* fc2w_in = d_in[12];
    const void* fc2b_in = d_in[13];
    const void* fclw_in = d_in[14];
    const void* fclb_in = d_in[15];

    char* ws = (char*)d_ws;
    size_t o = 0;
    auto alloc = [&](size_t b) { size_t r = o; o += (b + 255) & ~(size_t)255; return r; };

    const size_t NB2 = (size_t)N_NODES * DIM * 2;
    const size_t o_flag   = alloc(4);
    const size_t o_xbf    = alloc(NB2);
    const size_t o_A0     = alloc(NB2);
    const size_t o_A1     = alloc(NB2);
    const size_t o_A2     = alloc(NB2);
    const size_t o_B0     = alloc(NB2);
    const size_t o_B1     = alloc(NB2);
    const size_t o_Wt     = alloc((size_t)NSETS * NLAYERS * DIM * DIM * 4);
    const size_t o_Wf_hi  = alloc((size_t)NSETS * NLAYERS * 384 * DIM * 2);
    const size_t o_Wf_lo  = alloc((size_t)NSETS * NLAYERS * 384 * DIM * 2);
    const size_t o_whh_hi = alloc((size_t)NSETS * 384 * DIM * 2);
    const size_t o_whh_lo = alloc((size_t)NSETS * 384 * DIM * 2);
    const size_t o_bih    = alloc((size_t)NSETS * 384 * 4);
    const size_t o_bhh    = alloc((size_t)NSETS * 384 * 4);
    const size_t o_fc1w   = alloc(10320 * 4);
    const size_t o_fc1b   = alloc(80 * 4);
    const size_t o_fc2w   = alloc(6400 * 4);
    const size_t o_fc2b   = alloc(80 * 4);
    const size_t o_fclw   = alloc(160 * 4);
    const size_t o_fclb   = alloc(2 * 4);
    const size_t o_ptf    = alloc(64 * 4);
    const size_t o_cnt    = alloc(((size_t)3 * N_NODES + 1) * 4);
    const size_t o_cursor = alloc((size_t)3 * N_NODES * 4);
    const size_t o_col    = alloc((size_t)N_EDGES * 4);
    const int    nb_scan  = (3 * N_NODES + 1023) / 1024;
    const size_t o_part   = alloc((size_t)nb_scan * 4);
    const size_t o_pooled = alloc((size_t)NGRAPH * DIM * 4);
    const size_t o_gcnt   = alloc((size_t)NGRAPH * 4);

    if (ws_size < o) {
        fprintf(stderr, "GGNN kernel: workspace too small: need %zu, have %zu\n", o, ws_size);
        return;
    }

    int*   flag   = (int*)(ws + o_flag);
    u16*   xbf    = (u16*)(ws + o_xbf);
    u16*   A0     = (u16*)(ws + o_A0);
    u16*   A1     = (u16*)(ws + o_A1);
    u16*   A2     = (u16*)(ws + o_A2);
    u16*   B0     = (u16*)(ws + o_B0);
    u16*   B1     = (u16*)(ws + o_B1);
    float* Wt     = (float*)(ws + o_Wt);
    u16*   Wf_hi  = (u16*)(ws + o_Wf_hi);
    u16*   Wf_lo  = (u16*)(ws + o_Wf_lo);
    u16*   whh_hi = (u16*)(ws + o_whh_hi);
    u16*   whh_lo = (u16*)(ws + o_whh_lo);
    float* bihf   = (float*)(ws + o_bih);
    float* bhhf   = (float*)(ws + o_bhh);
    float* fc1wf  = (float*)(ws + o_fc1w);
    float* fc1bf  = (float*)(ws + o_fc1b);
    float* fc2wf  = (float*)(ws + o_fc2w);
    float* fc2bf  = (float*)(ws + o_fc2b);
    float* fclwf  = (float*)(ws + o_fclw);
    float* fclbf  = (float*)(ws + o_fclb);
    float* ptf    = (float*)(ws + o_ptf);
    int*   cnt    = (int*)(ws + o_cnt);
    int*   rp     = cnt;
    int*   cursor = (int*)(ws + o_cursor);
    int*   col    = (int*)(ws + o_col);
    int*   part   = (int*)(ws + o_part);
    float* pooled = (float*)(ws + o_pooled);
    int*   gcnt   = (int*)(ws + o_gcnt);

    hipMemsetAsync(cnt, 0, (size_t)3 * N_NODES * 4, stream);
    hipMemsetAsync(pooled, 0, (o_gcnt - o_pooled) + (size_t)NGRAPH * 4, stream);

    k_detect<<<1, 256, 0, stream>>>((const u16*)x_in, flag);

    // converts + weight prep
    k_to_bf<<<(N_NODES * DIM + 2047) / 2048, 256, 0, stream>>>(x_in, xbf, N_NODES * DIM, flag);
    k_transW<<<(NSETS * NLAYERS * DIM * DIM + 255) / 256, 256, 0, stream>>>(W_in, Wt, flag);
    k_fuse<<<(NSETS * NLAYERS * 384 * DIM) / 256, 256, 0, stream>>>(Wt, wih_in, Wf_hi, Wf_lo, flag);
    k_prep_G<<<(NSETS * 384 * DIM + 255) / 256, 256, 0, stream>>>(whh_in, whh_hi, whh_lo, flag);
    k_convert<<<(NSETS * 384 + 255) / 256, 256, 0, stream>>>(bih_in, bihf, NSETS * 384, flag);
    k_convert<<<(NSETS * 384 + 255) / 256, 256, 0, stream>>>(bhh_in, bhhf, NSETS * 384, flag);
    k_convert<<<(10320 + 255) / 256, 256, 0, stream>>>(fc1w_in, fc1wf, 10320, flag);
    k_convert<<<1, 256, 0, stream>>>(fc1b_in, fc1bf, 80, flag);
    k_convert<<<(6400 + 255) / 256, 256, 0, stream>>>(fc2w_in, fc2wf, 6400, flag);
    k_convert<<<1, 256, 0, stream>>>(fc2b_in, fc2bf, 80, flag);
    k_convert<<<1, 256, 0, stream>>>(fclw_in, fclwf, 160, flag);
    k_convert<<<1, 256, 0, stream>>>(fclb_in, fclbf, 2, flag);
    k_convert<<<1, 256, 0, stream>>>(pt_in, ptf, 64, flag);

    // CSR build
    k_deg<<<(N_EDGES + 255) / 256, 256, 0, stream>>>(ei, attr, cnt);
    k_scan1<<<nb_scan, 1024, 0, stream>>>(cnt, rp, part, 3 * N_NODES);
    k_scan2<<<1, 1024, 0, stream>>>(part, nb_scan);
    k_scan3<<<nb_scan, 1024, 0, stream>>>(rp, cursor, part, 3 * N_NODES);
    k_fill<<<(N_EDGES + 255) / 256, 256, 0, stream>>>(ei, attr, cursor, col);

    // GGC passes
    for (int pass = 0; pass < NPASS; ++pass) {
        k_gather<<<3 * GT, 256, 0, stream>>>(xbf, xbf, xbf, A0, A1, A2, rp, col);
        k_gemm<<<3 * MT, 512, 0, stream>>>(A0, A1, A2, xbf, xbf, xbf, A0, A1, A2,
                                           Wf_hi, Wf_lo, whh_hi, whh_lo, bihf, bhhf, 0);
        k_gather<<<3 * GT, 256, 0, stream>>>(A0, A1, A2, B0, B1, xbf, rp, col);
        k_gemm<<<3 * MT, 512, 0, stream>>>(B0, B1, xbf, A0, A1, A2, A0, A1, A2,
                                           Wf_hi, Wf_lo, whh_hi, whh_lo, bihf, bhhf, 1);
        k_avg3<<<(N_NODES * DIM / 8) / 256, 256, 0, stream>>>(A0, A1, A2, xbf);
    }

    // pooling + head
    k_pool<<<MT, 256, 0, stream>>>(xbf, batch, pooled, gcnt);
    k_head<<<1, 256, 0, stream>>>(pooled, gcnt, ptf, fc1wf, fc1bf, fc2wf, fc2bf,
                                  fclwf, fclbf, d_out, flag);
}

// Round 10
// 1310.851 us; speedup vs baseline: 1.4189x; 1.2185x over previous
//
#include <hip/hip_runtime.h>
#include <cstdio>
#include <cstdint>

#define N_NODES 100000
#define N_EDGES 600000
#define DIM     128
#define NSETS   3
#define NLAYERS 2
#define NGRAPH  64
#define NPASS   2
#define SP      136       // LDS row stride in shorts
#define GT      3125      // gather tiles (32 nodes each)
#define MT      1563      // gemm tiles (64 nodes each)

typedef __bf16 bf16x8 __attribute__((ext_vector_type(8)));
typedef float  f32x4  __attribute__((ext_vector_type(4)));
typedef unsigned short u16;

static __device__ __forceinline__ float bf2f(u16 u) {
    return __uint_as_float(((uint32_t)u) << 16);
}
static __device__ __forceinline__ u16 f2bf(float f) {
    uint32_t u = __float_as_uint(f);
    uint32_t r = (u + 0x7FFFu + ((u >> 16) & 1u)) >> 16;
    return (u16)r;
}
static __device__ __forceinline__ uint32_t packbf(float lo, float hi) {
    return (uint32_t)f2bf(lo) | ((uint32_t)f2bf(hi) << 16);
}
static __device__ __forceinline__ void unpack_add(uint32_t u, float& a0, float& a1) {
    a0 += __uint_as_float(u << 16);
    a1 += __uint_as_float(u & 0xFFFF0000u);
}
static __device__ __forceinline__ float sigmoidf_(float x) {
    return 1.0f / (1.0f + __expf(-x));
}
static __device__ __forceinline__ float tanhf_(float x) {
    return 1.0f - 2.0f / (__expf(2.0f * x) + 1.0f);
}

// ---------------- dtype detection ----------------
__global__ void k_detect(const u16* __restrict__ x, int* __restrict__ flag) {
    __shared__ float red[256];
    float m = 0.0f;
    for (int i = threadIdx.x; i < 8192; i += 256) {
        float f = __uint_as_float(((uint32_t)x[i]) << 16);
        f = fabsf(f);
        if (isnan(f)) f = 3.0e38f;
        m = fmaxf(m, f);
    }
    red[threadIdx.x] = m;
    __syncthreads();
    for (int off = 128; off > 0; off >>= 1) {
        if (threadIdx.x < off) red[threadIdx.x] = fmaxf(red[threadIdx.x], red[threadIdx.x + off]);
        __syncthreads();
    }
    if (threadIdx.x == 0) flag[0] = (red[0] < 1.0e6f) ? 1 : 0;
}

// ---------------- converts ----------------
__global__ void k_convert(const void* __restrict__ src, float* __restrict__ dst,
                          int n, const int* __restrict__ flag) {
    const int f = *flag;
    for (int i = blockIdx.x * blockDim.x + threadIdx.x; i < n; i += gridDim.x * blockDim.x) {
        float v;
        if (f) v = bf2f(((const u16*)src)[i]);
        else   v = ((const float*)src)[i];
        dst[i] = v;
    }
}

__global__ void k_to_bf(const void* __restrict__ src, u16* __restrict__ dst,
                        int n, const int* __restrict__ flag) {
    const int f = *flag;
    for (int i = blockIdx.x * blockDim.x + threadIdx.x; i < n; i += gridDim.x * blockDim.x) {
        if (f) dst[i] = ((const u16*)src)[i];
        else   dst[i] = f2bf(((const float*)src)[i]);
    }
}

// W raw [S][L][j][d] -> Wt fp32 [sl][d][j]
__global__ void k_transW(const void* __restrict__ src, float* __restrict__ dst,
                         const int* __restrict__ flag) {
    const int total = NSETS * NLAYERS * DIM * DIM;
    const int f = *flag;
    for (int i = blockIdx.x * blockDim.x + threadIdx.x; i < total; i += gridDim.x * blockDim.x) {
        const int sl = i >> 14;
        const int rem = i & 16383;
        const int d = rem >> 7;
        const int j = rem & 127;
        const int si = (sl << 14) + j * 128 + d;
        float v;
        if (f) v = bf2f(((const u16*)src)[si]);
        else   v = ((const float*)src)[si];
        dst[i] = v;
    }
}

// Wf[sl][n][j] = sum_d wih[s][n][d] * Wt[sl][d][j]
__global__ void k_fuse(const float* __restrict__ Wt, const void* __restrict__ wih_raw,
                       u16* __restrict__ hi, u16* __restrict__ lo,
                       const int* __restrict__ flag) {
    const int f = *flag;
    const int i = blockIdx.x * 256 + threadIdx.x;
    const int sl = i / 49152;
    const int rem = i - sl * 49152;
    const int n = rem >> 7;
    const int j = rem & 127;
    const int s = sl >> 1;
    const float* wt = Wt + (sl << 14) + j;
    const int wb = (s * 384 + n) * 128;
    float acc = 0.0f;
#pragma unroll 8
    for (int d = 0; d < 128; ++d) {
        float wv;
        if (f) wv = bf2f(((const u16*)wih_raw)[wb + d]);
        else   wv = ((const float*)wih_raw)[wb + d];
        acc = fmaf(wv, wt[d * 128], acc);
    }
    u16 h = f2bf(acc);
    hi[i] = h;
    lo[i] = f2bf(acc - bf2f(h));
}

// whh: [S][384][128] -> hi/lo bf16
__global__ void k_prep_G(const void* __restrict__ src, u16* __restrict__ hi,
                         u16* __restrict__ lo, const int* __restrict__ flag) {
    const int total = NSETS * 384 * DIM;
    const int f = *flag;
    for (int i = blockIdx.x * blockDim.x + threadIdx.x; i < total; i += gridDim.x * blockDim.x) {
        float v;
        if (f) v = bf2f(((const u16*)src)[i]);
        else   v = ((const float*)src)[i];
        u16 h = f2bf(v);
        hi[i] = h;
        lo[i] = f2bf(v - bf2f(h));
    }
}

// ---------------- CSR build ----------------
__global__ void k_deg(const int* __restrict__ ei, const int* __restrict__ attr,
                      int* __restrict__ cnt) {
    int e = blockIdx.x * 256 + threadIdx.x;
    if (e < N_EDGES) {
        int t = attr[e];
        int d = ei[N_EDGES + e];
        atomicAdd(&cnt[t * N_NODES + d], 1);
    }
}

__global__ void k_scan1(const int* __restrict__ cnt, int* __restrict__ rp,
                        int* __restrict__ part, int n) {
    __shared__ int buf[1024];
    int gid = blockIdx.x * 1024 + threadIdx.x;
    int v = (gid < n) ? cnt[gid] : 0;
    buf[threadIdx.x] = v;
    __syncthreads();
    for (int off = 1; off < 1024; off <<= 1) {
        int t = (threadIdx.x >= off) ? buf[threadIdx.x - off] : 0;
        __syncthreads();
        buf[threadIdx.x] += t;
        __syncthreads();
    }
    if (gid < n) rp[gid] = buf[threadIdx.x] - v;
    if (threadIdx.x == 1023) part[blockIdx.x] = buf[1023];
}

__global__ void k_scan2(int* __restrict__ part, int nb) {
    __shared__ int buf[1024];
    int v = (threadIdx.x < nb) ? part[threadIdx.x] : 0;
    buf[threadIdx.x] = v;
    __syncthreads();
    for (int off = 1; off < 1024; off <<= 1) {
        int t = (threadIdx.x >= off) ? buf[threadIdx.x - off] : 0;
        __syncthreads();
        buf[threadIdx.x] += t;
        __syncthreads();
    }
    if (threadIdx.x < nb) part[threadIdx.x] = buf[threadIdx.x] - v;
}

__global__ void k_scan3(int* __restrict__ rp, int* __restrict__ cursor,
                        const int* __restrict__ part, int n) {
    int gid = blockIdx.x * 1024 + threadIdx.x;
    if (gid < n) {
        int v = rp[gid] + part[blockIdx.x];
        rp[gid] = v;
        cursor[gid] = v;
    }
    if (gid == 0) rp[n] = N_EDGES;
}

__global__ void k_fill(const int* __restrict__ ei, const int* __restrict__ attr,
                       int* __restrict__ cursor, int* __restrict__ col) {
    int e = blockIdx.x * 256 + threadIdx.x;
    if (e < N_EDGES) {
        int t = attr[e];
        int d = ei[N_EDGES + e];
        int s = ei[e];
        int pos = atomicAdd(&cursor[t * N_NODES + d], 1);
        col[pos] = s;
    }
}

// ---------------- gather ----------------
__global__ void __launch_bounds__(256, 6)
k_gather(const u16* __restrict__ s0, const u16* __restrict__ s1, const u16* __restrict__ s2,
         u16* __restrict__ d0, u16* __restrict__ d1, u16* __restrict__ d2,
         const int* __restrict__ rp, const int* __restrict__ colarr) {
    const int bx = blockIdx.x;
    const int set = bx / GT;
    const int tile = bx - set * GT;
    const u16* __restrict__ src = (set == 0) ? s0 : (set == 1) ? s1 : s2;
    u16* __restrict__ dst = (set == 0) ? d0 : (set == 1) ? d1 : d2;
    const int* __restrict__ rp_s = rp + set * N_NODES;

    const int nl = threadIdx.x >> 3;
    const int q  = threadIdx.x & 7;
    const int gn = tile * 32 + nl;

    float a[16];
#pragma unroll
    for (int j = 0; j < 16; ++j) a[j] = 0.0f;

    const int beg = rp_s[gn], end = rp_s[gn + 1];
    int dg = end - beg; if (dg < 1) dg = 1;
    const float inv = 1.0f / (float)dg;

    int e = beg;
    for (; e + 2 <= end; e += 2) {
        const int c0 = colarr[e];
        const int c1 = colarr[e + 1];
        const uint4* m0 = (const uint4*)(src + (size_t)c0 * DIM + q * 16);
        const uint4* m1 = (const uint4*)(src + (size_t)c1 * DIM + q * 16);
        uint4 v0 = m0[0], v1 = m0[1], w0 = m1[0], w1 = m1[1];
        unpack_add(v0.x, a[0], a[1]);   unpack_add(v0.y, a[2], a[3]);
        unpack_add(v0.z, a[4], a[5]);   unpack_add(v0.w, a[6], a[7]);
        unpack_add(v1.x, a[8], a[9]);   unpack_add(v1.y, a[10], a[11]);
        unpack_add(v1.z, a[12], a[13]); unpack_add(v1.w, a[14], a[15]);
        unpack_add(w0.x, a[0], a[1]);   unpack_add(w0.y, a[2], a[3]);
        unpack_add(w0.z, a[4], a[5]);   unpack_add(w0.w, a[6], a[7]);
        unpack_add(w1.x, a[8], a[9]);   unpack_add(w1.y, a[10], a[11]);
        unpack_add(w1.z, a[12], a[13]); unpack_add(w1.w, a[14], a[15]);
    }
    if (e < end) {
        const int c0 = colarr[e];
        const uint4* m0 = (const uint4*)(src + (size_t)c0 * DIM + q * 16);
        uint4 v0 = m0[0], v1 = m0[1];
        unpack_add(v0.x, a[0], a[1]);   unpack_add(v0.y, a[2], a[3]);
        unpack_add(v0.z, a[4], a[5]);   unpack_add(v0.w, a[6], a[7]);
        unpack_add(v1.x, a[8], a[9]);   unpack_add(v1.y, a[10], a[11]);
        unpack_add(v1.z, a[12], a[13]); unpack_add(v1.w, a[14], a[15]);
    }
#pragma unroll
    for (int j = 0; j < 16; ++j) a[j] *= inv;

    uint4* d = (uint4*)(dst + (size_t)gn * DIM + q * 16);
    d[0] = make_uint4(packbf(a[0], a[1]), packbf(a[2], a[3]),
                      packbf(a[4], a[5]), packbf(a[6], a[7]));
    d[1] = make_uint4(packbf(a[8], a[9]), packbf(a[10], a[11]),
                      packbf(a[12], a[13]), packbf(a[14], a[15]));
}

// ---------------- fused GEMM+GRU: 512 threads, 16 cols/wave ----------------
// r,z gates: single-bf16 weights, merged into ONE K-pass (shared frag loads).
// n gate: hi/lo bf16 weights (precision-critical tanh path).
__global__ void __launch_bounds__(512, 4)
k_gemm(const u16* __restrict__ g0, const u16* __restrict__ g1, const u16* __restrict__ g2,
       const u16* __restrict__ o0, const u16* __restrict__ o1, const u16* __restrict__ o2,
       u16* __restrict__ d0, u16* __restrict__ d1, u16* __restrict__ d2,
       const u16* __restrict__ Wf_hi, const u16* __restrict__ Wf_lo,
       const u16* __restrict__ whh_hi, const u16* __restrict__ whh_lo,
       const float* __restrict__ bih, const float* __restrict__ bhh, int layer)
{
    __shared__ u16 sA[64 * SP];   // agg (bf16) -> out staging
    __shared__ u16 sH[64 * SP];   // own h

    const int tid  = threadIdx.x;
    const int lane = tid & 63;
    const int wv   = tid >> 6;        // 0..7
    const int l15  = lane & 15;
    const int quad = lane >> 4;
    const int col  = wv * 16 + l15;   // this lane's output column

    const int set  = blockIdx.x / MT;
    const int tile = blockIdx.x - set * MT;
    const int n0   = tile * 64;

    const u16* __restrict__ gsrc = (set == 0) ? g0 : (set == 1) ? g1 : g2;
    const u16* __restrict__ osrc = (set == 0) ? o0 : (set == 1) ? o1 : o2;
    u16* __restrict__ dst        = (set == 0) ? d0 : (set == 1) ? d1 : d2;
    const u16* wf_hi = Wf_hi + (size_t)(set * NLAYERS + layer) * 384 * DIM;
    const u16* wf_lo = Wf_lo + (size_t)(set * NLAYERS + layer) * 384 * DIM;
    const u16* wh_hi = whh_hi + (size_t)set * 384 * DIM;
    const u16* wh_lo = whh_lo + (size_t)set * 384 * DIM;
    const float* bi_s = bih + (size_t)set * 384;
    const float* bh_s = bhh + (size_t)set * 384;

    // staging coords: 64 rows x 8 chunks of 16 u16 (32 B)
    const int srow = tid >> 3;
    const int sq   = tid & 7;
    const int sgn  = n0 + srow;

    // ---- stage agg + own ----
    {
        uint4 va0 = {0,0,0,0}, va1 = {0,0,0,0}, vh0 = {0,0,0,0}, vh1 = {0,0,0,0};
        if (sgn < N_NODES) {
            const uint4* ga = (const uint4*)(gsrc + (size_t)sgn * DIM + sq * 16);
            const uint4* oh = (const uint4*)(osrc + (size_t)sgn * DIM + sq * 16);
            va0 = ga[0]; va1 = ga[1]; vh0 = oh[0]; vh1 = oh[1];
        }
        uint4* da = (uint4*)&sA[srow * SP + sq * 16];
        uint4* dh = (uint4*)&sH[srow * SP + sq * 16];
        da[0] = va0; da[1] = va1; dh[0] = vh0; dh[1] = vh1;
    }
    __syncthreads();

    // biases for this lane's column
    const float b_r = bi_s[col] + bh_s[col];
    const float b_z = bi_s[128 + col] + bh_s[128 + col];
    const float bin = bi_s[256 + col];
    const float bhn = bh_s[256 + col];

    uint32_t rz[4][4];   // [mt][r]: low16 = r, high16 = z (bf16)

    // ---- r and z gates: merged single K-pass, single-bf16 weights ----
    {
        f32x4 acc_r[4], acc_z[4];
#pragma unroll
        for (int mt = 0; mt < 4; ++mt) {
            acc_r[mt] = (f32x4){0.f, 0.f, 0.f, 0.f};
            acc_z[mt] = (f32x4){0.f, 0.f, 0.f, 0.f};
        }
#pragma unroll
        for (int ks = 0; ks < 4; ++ks) {
            const int k0 = ks * 32;
            bf16x8 ag[4], ah[4];
#pragma unroll
            for (int mt = 0; mt < 4; ++mt) {
                ag[mt] = *(const bf16x8*)&sA[(mt * 16 + l15) * SP + k0 + quad * 8];
                ah[mt] = *(const bf16x8*)&sH[(mt * 16 + l15) * SP + k0 + quad * 8];
            }
            const size_t br = (size_t)col * 128 + k0 + quad * 8;
            const size_t bz = (size_t)(128 + col) * 128 + k0 + quad * 8;
            bf16x8 fi_r = *(const bf16x8*)(wf_hi + br);
            bf16x8 hh_r = *(const bf16x8*)(wh_hi + br);
            bf16x8 fi_z = *(const bf16x8*)(wf_hi + bz);
            bf16x8 hh_z = *(const bf16x8*)(wh_hi + bz);
#pragma unroll
            for (int mt = 0; mt < 4; ++mt) {
                acc_r[mt] = __builtin_amdgcn_mfma_f32_16x16x32_bf16(ag[mt], fi_r, acc_r[mt], 0, 0, 0);
                acc_r[mt] = __builtin_amdgcn_mfma_f32_16x16x32_bf16(ah[mt], hh_r, acc_r[mt], 0, 0, 0);
                acc_z[mt] = __builtin_amdgcn_mfma_f32_16x16x32_bf16(ag[mt], fi_z, acc_z[mt], 0, 0, 0);
                acc_z[mt] = __builtin_amdgcn_mfma_f32_16x16x32_bf16(ah[mt], hh_z, acc_z[mt], 0, 0, 0);
            }
        }
#pragma unroll
        for (int mt = 0; mt < 4; ++mt)
#pragma unroll
            for (int r = 0; r < 4; ++r)
                rz[mt][r] = packbf(sigmoidf_(acc_r[mt][r] + b_r),
                                   sigmoidf_(acc_z[mt][r] + b_z));
    }

    // ---- n gate: hi/lo weights, separate i/h accumulators ----
    f32x4 acc_i[4], acc_h[4];
#pragma unroll
    for (int mt = 0; mt < 4; ++mt) {
        acc_i[mt] = (f32x4){0.f, 0.f, 0.f, 0.f};
        acc_h[mt] = (f32x4){0.f, 0.f, 0.f, 0.f};
    }
#pragma unroll
    for (int ks = 0; ks < 4; ++ks) {
        const int k0 = ks * 32;
        bf16x8 ag[4], ah[4];
#pragma unroll
        for (int mt = 0; mt < 4; ++mt) {
            ag[mt] = *(const bf16x8*)&sA[(mt * 16 + l15) * SP + k0 + quad * 8];
            ah[mt] = *(const bf16x8*)&sH[(mt * 16 + l15) * SP + k0 + quad * 8];
        }
        const size_t boff = (size_t)(256 + col) * 128 + k0 + quad * 8;
        bf16x8 fi_h = *(const bf16x8*)(wf_hi + boff);
        bf16x8 fi_l = *(const bf16x8*)(wf_lo + boff);
        bf16x8 hh_h = *(const bf16x8*)(wh_hi + boff);
        bf16x8 hh_l = *(const bf16x8*)(wh_lo + boff);
#pragma unroll
        for (int mt = 0; mt < 4; ++mt) {
            acc_i[mt] = __builtin_amdgcn_mfma_f32_16x16x32_bf16(ag[mt], fi_h, acc_i[mt], 0, 0, 0);
            acc_i[mt] = __builtin_amdgcn_mfma_f32_16x16x32_bf16(ag[mt], fi_l, acc_i[mt], 0, 0, 0);
            acc_h[mt] = __builtin_amdgcn_mfma_f32_16x16x32_bf16(ah[mt], hh_h, acc_h[mt], 0, 0, 0);
            acc_h[mt] = __builtin_amdgcn_mfma_f32_16x16x32_bf16(ah[mt], hh_l, acc_h[mt], 0, 0, 0);
        }
    }

    // ---- combine -> out (bf16) into sA, then coalesced store ----
    __syncthreads();   // all waves done reading sA/sH fragments
#pragma unroll
    for (int mt = 0; mt < 4; ++mt)
#pragma unroll
        for (int r = 0; r < 4; ++r) {
            const int row = mt * 16 + quad * 4 + r;
            const float i_n = acc_i[mt][r] + bin;
            const float h_n = acc_h[mt][r] + bhn;
            const uint32_t p = rz[mt][r];
            const float rr = bf2f((u16)(p & 0xFFFFu));
            const float zz = bf2f((u16)(p >> 16));
            const float nn = tanhf_(i_n + rr * h_n);
            const float hv = bf2f(sH[row * SP + col]);
            sA[row * SP + col] = f2bf((1.0f - zz) * nn + zz * hv);
        }
    __syncthreads();
    if (sgn < N_NODES) {
        const uint4* sp = (const uint4*)&sA[srow * SP + sq * 16];
        uint4* d = (uint4*)(dst + (size_t)sgn * DIM + sq * 16);
        d[0] = sp[0]; d[1] = sp[1];
    }
}

// ---------------- x = (a+b+c)/3 (bf16) ----------------
__global__ void k_avg3(const u16* __restrict__ a, const u16* __restrict__ b,
                       const u16* __restrict__ c, u16* __restrict__ d) {
    const int i = blockIdx.x * 256 + threadIdx.x;
    const uint4 va = ((const uint4*)a)[i];
    const uint4 vb = ((const uint4*)b)[i];
    const uint4 vc = ((const uint4*)c)[i];
    const float third = 1.0f / 3.0f;
    auto comb = [&](uint32_t x, uint32_t y, uint32_t z) -> uint32_t {
        float l = 0.f, h = 0.f;
        unpack_add(x, l, h); unpack_add(y, l, h); unpack_add(z, l, h);
        return packbf(l * third, h * third);
    };
    uint4 vo;
    vo.x = comb(va.x, vb.x, vc.x);
    vo.y = comb(va.y, vb.y, vc.y);
    vo.z = comb(va.z, vb.z, vc.z);
    vo.w = comb(va.w, vb.w, vc.w);
    ((uint4*)d)[i] = vo;
}

// ---------------- pooling (bf16 x) ----------------
__global__ void k_pool(const u16* __restrict__ xf, const int* __restrict__ batch,
                       float* __restrict__ pooled, int* __restrict__ gcnt) {
    const int tid = threadIdx.x;
    const int f = tid & 127;
    const int half = tid >> 7;
    const int nstart = blockIdx.x * 64 + half * 32;
    float accv = 0.0f;
    int curg = -1, cnt = 0;
    for (int t = 0; t < 32; ++t) {
        const int n = nstart + t;
        if (n >= N_NODES) break;
        const int g = batch[n];
        if (g != curg) {
            if (curg >= 0) {
                atomicAdd(&pooled[curg * DIM + f], accv);
                if (f == 0) atomicAdd(&gcnt[curg], cnt);
            }
            curg = g; accv = 0.0f; cnt = 0;
        }
        accv += bf2f(xf[(size_t)n * DIM + f]);
        cnt++;
    }
    if (curg >= 0) {
        atomicAdd(&pooled[curg * DIM + f], accv);
        if (f == 0) atomicAdd(&gcnt[curg], cnt);
    }
}

// ---------------- MLP head ----------------
__global__ void k_head(const float* __restrict__ pooled, const int* __restrict__ gcnt,
                       const float* __restrict__ ptf,
                       const float* __restrict__ fc1w, const float* __restrict__ fc1b,
                       const float* __restrict__ fc2w, const float* __restrict__ fc2b,
                       const float* __restrict__ fclw, const float* __restrict__ fclb,
                       void* __restrict__ out, const int* __restrict__ flag) {
    __shared__ float xh[64 * 129];
    __shared__ float h1[64 * 80];
    const int tid = threadIdx.x;
    for (int i = tid; i < 64 * 128; i += 256) {
        const int g = i >> 7;
        int c = gcnt[g]; if (c < 1) c = 1;
        xh[g * 129 + (i & 127)] = pooled[i] / (float)c;
    }
    for (int g = tid; g < 64; g += 256) xh[g * 129 + 128] = ptf[g];
    __syncthreads();
    for (int i = tid; i < 64 * 80; i += 256) {
        const int g = i / 80, c = i - g * 80;
        float s = fc1b[c];
        const float* xr = &xh[g * 129];
        const float* wr = &fc1w[c * 129];
        for (int k = 0; k < 129; ++k) s += xr[k] * wr[k];
        h1[i] = (s > 0.0f) ? s : 0.01f * s;
    }
    __syncthreads();
    float* h2 = xh;
    for (int i = tid; i < 64 * 80; i += 256) {
        const int g = i / 80, c = i - g * 80;
        float s = fc2b[c];
        const float* hr = &h1[g * 80];
        const float* wr = &fc2w[c * 80];
        for (int k = 0; k < 80; ++k) s += hr[k] * wr[k];
        h2[i] = (s > 0.0f) ? s : 0.01f * s;
    }
    __syncthreads();
    for (int i = tid; i < 128; i += 256) {
        const int g = i >> 1, c = i & 1;
        float s = fclb[c];
        const float* hr = &h2[g * 80];
        const float* wr = &fclw[c * 80];
        for (int k = 0; k < 80; ++k) s += hr[k] * wr[k];
        if (*flag) ((u16*)out)[i] = f2bf(s);
        else       ((float*)out)[i] = s;
    }
}

// ---------------- launcher ----------------
extern "C" void kernel_launch(void* const* d_in, const int* in_sizes, int n_in,
                              void* d_out, int out_size, void* d_ws, size_t ws_size,
                              hipStream_t stream) {
    if (n_in < 16) return;
    const void* x_in    = d_in[0];
    const int*  ei      = (const int*)d_in[1];
    const int*  attr    = (const int*)d_in[2];
    const int*  batch   = (const int*)d_in[3];
    const void* pt_in   = d_in[4];
    const void* W_in    = d_in[5];
    const void* wih_in  = d_in[6];
    const void* whh_in  = d_in[7];
    const void* bih_in  = d_in[8];
    const void* bhh_in  = d_in[9];
    const void* fc1w_in = d_in[10];
    const void* fc1b_in = d_in[11];
    const void* fc2w_in = d_in[12];
    const void* fc2b_in = d_in[13];
    const void* fclw_in = d_in[14];
    const void* fclb_in = d_in[15];

    char* ws = (char*)d_ws;
    size_t o = 0;
    auto alloc = [&](size_t b) { size_t r = o; o += (b + 255) & ~(size_t)255; return r; };

    const size_t NB2 = (size_t)N_NODES * DIM * 2;
    const size_t o_flag   = alloc(4);
    const size_t o_xbf    = alloc(NB2);
    const size_t o_A0     = alloc(NB2);
    const size_t o_A1     = alloc(NB2);
    const size_t o_A2     = alloc(NB2);
    const size_t o_B0     = alloc(NB2);
    const size_t o_B1     = alloc(NB2);
    const size_t o_Wt     = alloc((size_t)NSETS * NLAYERS * DIM * DIM * 4);
    const size_t o_Wf_hi  = alloc((size_t)NSETS * NLAYERS * 384 * DIM * 2);
    const size_t o_Wf_lo  = alloc((size_t)NSETS * NLAYERS * 384 * DIM * 2);
    const size_t o_whh_hi = alloc((size_t)NSETS * 384 * DIM * 2);
    const size_t o_whh_lo = alloc((size_t)NSETS * 384 * DIM * 2);
    const size_t o_bih    = alloc((size_t)NSETS * 384 * 4);
    const size_t o_bhh    = alloc((size_t)NSETS * 384 * 4);
    const size_t o_fc1w   = alloc(10320 * 4);
    const size_t o_fc1b   = alloc(80 * 4);
    const size_t o_fc2w   = alloc(6400 * 4);
    const size_t o_fc2b   = alloc(80 * 4);
    const size_t o_fclw   = alloc(160 * 4);
    const size_t o_fclb   = alloc(2 * 4);
    const size_t o_ptf    = alloc(64 * 4);
    const size_t o_cnt    = alloc(((size_t)3 * N_NODES + 1) * 4);
    const size_t o_cursor = alloc((size_t)3 * N_NODES * 4);
    const size_t o_col    = alloc((size_t)N_EDGES * 4);
    const int    nb_scan  = (3 * N_NODES + 1023) / 1024;
    const size_t o_part   = alloc((size_t)nb_scan * 4);
    const size_t o_pooled = alloc((size_t)NGRAPH * DIM * 4);
    const size_t o_gcnt   = alloc((size_t)NGRAPH * 4);

    if (ws_size < o) {
        fprintf(stderr, "GGNN kernel: workspace too small: need %zu, have %zu\n", o, ws_size);
        return;
    }

    int*   flag   = (int*)(ws + o_flag);
    u16*   xbf    = (u16*)(ws + o_xbf);
    u16*   A0     = (u16*)(ws + o_A0);
    u16*   A1     = (u16*)(ws + o_A1);
    u16*   A2     = (u16*)(ws + o_A2);
    u16*   B0     = (u16*)(ws + o_B0);
    u16*   B1     = (u16*)(ws + o_B1);
    float* Wt     = (float*)(ws + o_Wt);
    u16*   Wf_hi  = (u16*)(ws + o_Wf_hi);
    u16*   Wf_lo  = (u16*)(ws + o_Wf_lo);
    u16*   whh_hi = (u16*)(ws + o_whh_hi);
    u16*   whh_lo = (u16*)(ws + o_whh_lo);
    float* bihf   = (float*)(ws + o_bih);
    float* bhhf   = (float*)(ws + o_bhh);
    float* fc1wf  = (float*)(ws + o_fc1w);
    float* fc1bf  = (float*)(ws + o_fc1b);
    float* fc2wf  = (float*)(ws + o_fc2w);
    float* fc2bf  = (float*)(ws + o_fc2b);
    float* fclwf  = (float*)(ws + o_fclw);
    float* fclbf  = (float*)(ws + o_fclb);
    float* ptf    = (float*)(ws + o_ptf);
    int*   cnt    = (int*)(ws + o_cnt);
    int*   rp     = cnt;
    int*   cursor = (int*)(ws + o_cursor);
    int*   col    = (int*)(ws + o_col);
    int*   part   = (int*)(ws + o_part);
    float* pooled = (float*)(ws + o_pooled);
    int*   gcnt   = (int*)(ws + o_gcnt);

    hipMemsetAsync(cnt, 0, (size_t)3 * N_NODES * 4, stream);
    hipMemsetAsync(pooled, 0, (o_gcnt - o_pooled) + (size_t)NGRAPH * 4, stream);

    k_detect<<<1, 256, 0, stream>>>((const u16*)x_in, flag);

    // converts + weight prep
    k_to_bf<<<(N_NODES * DIM + 2047) / 2048, 256, 0, stream>>>(x_in, xbf, N_NODES * DIM, flag);
    k_transW<<<(NSETS * NLAYERS * DIM * DIM + 255) / 256, 256, 0, stream>>>(W_in, Wt, flag);
    k_fuse<<<(NSETS * NLAYERS * 384 * DIM) / 256, 256, 0, stream>>>(Wt, wih_in, Wf_hi, Wf_lo, flag);
    k_prep_G<<<(NSETS * 384 * DIM + 255) / 256, 256, 0, stream>>>(whh_in, whh_hi, whh_lo, flag);
    k_convert<<<(NSETS * 384 + 255) / 256, 256, 0, stream>>>(bih_in, bihf, NSETS * 384, flag);
    k_convert<<<(NSETS * 384 + 255) / 256, 256, 0, stream>>>(bhh_in, bhhf, NSETS * 384, flag);
    k_convert<<<(10320 + 255) / 256, 256, 0, stream>>>(fc1w_in, fc1wf, 10320, flag);
    k_convert<<<1, 256, 0, stream>>>(fc1b_in, fc1bf, 80, flag);
    k_convert<<<(6400 + 255) / 256, 256, 0, stream>>>(fc2w_in, fc2wf, 6400, flag);
    k_convert<<<1, 256, 0, stream>>>(fc2b_in, fc2bf, 80, flag);
    k_convert<<<1, 256, 0, stream>>>(fclw_in, fclwf, 160, flag);
    k_convert<<<1, 256, 0, stream>>>(fclb_in, fclbf, 2, flag);
    k_convert<<<1, 256, 0, stream>>>(pt_in, ptf, 64, flag);

    // CSR build
    k_deg<<<(N_EDGES + 255) / 256, 256, 0, stream>>>(ei, attr, cnt);
    k_scan1<<<nb_scan, 1024, 0, stream>>>(cnt, rp, part, 3 * N_NODES);
    k_scan2<<<1, 1024, 0, stream>>>(part, nb_scan);
    k_scan3<<<nb_scan, 1024, 0, stream>>>(rp, cursor, part, 3 * N_NODES);
    k_fill<<<(N_EDGES + 255) / 256, 256, 0, stream>>>(ei, attr, cursor, col);

    // GGC passes
    for (int pass = 0; pass < NPASS; ++pass) {
        k_gather<<<3 * GT, 256, 0, stream>>>(xbf, xbf, xbf, A0, A1, A2, rp, col);
        k_gemm<<<3 * MT, 512, 0, stream>>>(A0, A1, A2, xbf, xbf, xbf, A0, A1, A2,
                                           Wf_hi, Wf_lo, whh_hi, whh_lo, bihf, bhhf, 0);
        k_gather<<<3 * GT, 256, 0, stream>>>(A0, A1, A2, B0, B1, xbf, rp, col);
        k_gemm<<<3 * MT, 512, 0, stream>>>(B0, B1, xbf, A0, A1, A2, A0, A1, A2,
                                           Wf_hi, Wf_lo, whh_hi, whh_lo, bihf, bhhf, 1);
        k_avg3<<<(N_NODES * DIM / 8) / 256, 256, 0, stream>>>(A0, A1, A2, xbf);
    }

    // pooling + head
    k_pool<<<MT, 256, 0, stream>>>(xbf, batch, pooled, gcnt);
    k_head<<<1, 256, 0, stream>>>(pooled, gcnt, ptf, fc1wf, fc1bf, fc2wf, fc2bf,
                                  fclwf, fclbf, d_out, flag);
}